// Round 13
// baseline (828.357 us; speedup 1.0000x reference)
//
#include <hip/hip_runtime.h>
#include <hip/hip_bf16.h>

typedef _Float16 f16;
typedef _Float16 half8 __attribute__((ext_vector_type(8)));
typedef float f32x4 __attribute__((ext_vector_type(4)));

#define S_LEN 1024
#define DMODEL 512
#define NFFT   2048
#define RPB    2048     // rows per batch: f=1..1023 pairs + packed (DC.re, Nyq.re) in rows 0,1
#define RTOT   4096     // 2 batches -> exactly 32 row-tiles of 128
#define CPS    1064     // cpcm f-stride
#define NROW   2048     // B*S
#define NPART  4        // split-K partials for spectral GEMM (grid 512 = exactly 1 generation)

__device__ __forceinline__ float2 mkf2(float a, float b) { float2 r; r.x = a; r.y = b; return r; }
__device__ __forceinline__ int zp(int i) { return i + (i >> 5); }   // LDS bank-pad for FFT array
__device__ __forceinline__ float2 cmul(float2 w, float2 b) {
  return mkf2(b.x * w.x - b.y * w.y, b.x * w.y + b.y * w.x);
}
__device__ __forceinline__ float2 f2a(float2 a, float2 b) { return mkf2(a.x + b.x, a.y + b.y); }
__device__ __forceinline__ float2 f2s(float2 a, float2 b) { return mkf2(a.x - b.x, a.y - b.y); }

// async global->LDS (16B per lane). LDS dest must be wave-uniform base; lane writes at +lane*16.
__device__ __forceinline__ void gl16(const f16* g, f16* l) {
  __builtin_amdgcn_global_load_lds((const __attribute__((address_space(1))) void*)g,
                                   (__attribute__((address_space(3))) void*)l, 16, 0, 0);
}

// ---------------- FFT-2048 in LDS: 3x radix-8 + 1x radix-4, padded indexing ----------------
template<bool INV>
__device__ __forceinline__ void fft2048(float2* z, const float2* __restrict__ tw, int tid) {
  for (int i = tid; i < 2048; i += 256) {
    int j = (int)(__brev((unsigned)i) >> 21);
    if (i < j) { float2 a = z[zp(i)]; z[zp(i)] = z[zp(j)]; z[zp(j)] = a; }
  }
  __syncthreads();
#pragma unroll
  for (int r8 = 0; r8 < 3; ++r8) {       // fused stages (1,2,3),(4,5,6),(7,8,9)
    const int sl = 1 + 3 * r8;
    const int h = 1 << (sl - 1);
    {
      int q = tid;                        // 256 groups of 8, one per thread
      int j = q & (h - 1);
      int i0 = ((q >> (sl - 1)) << (sl + 2)) + j;
      float2 a0 = z[zp(i0)],         a1 = z[zp(i0 + h)];
      float2 a2 = z[zp(i0 + 2 * h)], a3 = z[zp(i0 + 3 * h)];
      float2 a4 = z[zp(i0 + 4 * h)], a5 = z[zp(i0 + 5 * h)];
      float2 a6 = z[zp(i0 + 6 * h)], a7 = z[zp(i0 + 7 * h)];
      float2 wA  = tw[j << (11 - sl)];
      float2 wB0 = tw[j << (10 - sl)];
      float2 wB1 = tw[(j + h) << (10 - sl)];
      float2 wC0 = tw[j << (9 - sl)];
      float2 wC1 = tw[(j + h) << (9 - sl)];
      float2 wC2 = tw[(j + 2 * h) << (9 - sl)];
      float2 wC3 = tw[(j + 3 * h) << (9 - sl)];
      if (INV) {
        wA.y = -wA.y; wB0.y = -wB0.y; wB1.y = -wB1.y;
        wC0.y = -wC0.y; wC1.y = -wC1.y; wC2.y = -wC2.y; wC3.y = -wC3.y;
      }
      float2 t;
      t = cmul(wA, a1); float2 b0 = f2a(a0, t), b1 = f2s(a0, t);
      t = cmul(wA, a3); float2 b2 = f2a(a2, t), b3 = f2s(a2, t);
      t = cmul(wA, a5); float2 b4 = f2a(a4, t), b5 = f2s(a4, t);
      t = cmul(wA, a7); float2 b6 = f2a(a6, t), b7 = f2s(a6, t);
      t = cmul(wB0, b2); float2 c0 = f2a(b0, t), c2 = f2s(b0, t);
      t = cmul(wB1, b3); float2 c1 = f2a(b1, t), c3 = f2s(b1, t);
      t = cmul(wB0, b6); float2 c4 = f2a(b4, t), c6 = f2s(b4, t);
      t = cmul(wB1, b7); float2 c5 = f2a(b5, t), c7 = f2s(b5, t);
      t = cmul(wC0, c4); z[zp(i0)]         = f2a(c0, t); z[zp(i0 + 4 * h)] = f2s(c0, t);
      t = cmul(wC1, c5); z[zp(i0 + h)]     = f2a(c1, t); z[zp(i0 + 5 * h)] = f2s(c1, t);
      t = cmul(wC2, c6); z[zp(i0 + 2 * h)] = f2a(c2, t); z[zp(i0 + 6 * h)] = f2s(c2, t);
      t = cmul(wC3, c7); z[zp(i0 + 3 * h)] = f2a(c3, t); z[zp(i0 + 7 * h)] = f2s(c3, t);
    }
    __syncthreads();
  }
  for (int q = tid; q < 512; q += 256) {  // final radix-4 round: stages (10,11)
    float2 a0 = z[zp(q)], a1 = z[zp(q + 512)], a2 = z[zp(q + 1024)], a3 = z[zp(q + 1536)];
    float2 w1 = tw[q << 1], w2 = tw[q], w3 = tw[q + 512];
    if (INV) { w1.y = -w1.y; w2.y = -w2.y; w3.y = -w3.y; }
    float2 t;
    t = cmul(w1, a1); float2 b0 = f2a(a0, t), b1 = f2s(a0, t);
    t = cmul(w1, a3); float2 b2 = f2a(a2, t), b3 = f2s(a2, t);
    t = cmul(w2, b2); z[zp(q)]        = f2a(b0, t); z[zp(q + 1024)] = f2s(b0, t);
    t = cmul(w3, b3); z[zp(q + 512)]  = f2a(b1, t); z[zp(q + 1536)] = f2s(b1, t);
  }
  __syncthreads();
}

// ---------------- init kernels ----------------
__global__ void k_twiddle(float2* tw) {
  int i = blockIdx.x * 256 + threadIdx.x;
  if (i < 1024) {
    float ang = -6.2831853071795864769f * (float)i / 2048.0f;
    tw[i] = mkf2(cosf(ang), sinf(ang));
  }
}

// rfft of phi columns (pairs packed into one complex FFT)
__global__ void k_fft_phi(const float* __restrict__ phi, float2* __restrict__ Vf,
                          const float2* __restrict__ tw) {
  __shared__ float2 z[2112];
  int tid = threadIdx.x;
  int k0 = blockIdx.x * 2;
  for (int t = tid; t < 1024; t += 256)
    z[zp(t)] = *(const float2*)(phi + (size_t)t * 16 + k0);
  for (int t = 1024 + tid; t < 2048; t += 256) z[zp(t)] = mkf2(0.f, 0.f);
  __syncthreads();
  fft2048<false>(z, tw, tid);
  for (int f = tid; f <= 1024; f += 256) {
    float2 zf = z[zp(f)], zc = z[zp((2048 - f) & 2047)];
    Vf[(size_t)k0 * 1025 + f]       = mkf2(0.5f * (zf.x + zc.x), 0.5f * (zf.y - zc.y));
    Vf[(size_t)(k0 + 1) * 1025 + f] = mkf2(0.5f * (zf.y + zc.y), 0.5f * (zc.x - zf.x));
  }
}

// cpcm[kb][f]: f=1..1023 standard complex scale; slot 0 packs (c_DC, c_Nyq) (both REAL).
__global__ void k_cpcm(const float2* __restrict__ Vf, const float* __restrict__ sigma,
                       float2* __restrict__ cpcm) {
  int idx = blockIdx.x * 256 + threadIdx.x;
  if (idx >= 32 * CPS) return;
  int kb = idx / CPS, f = idx - kb * CPS;
  int k = kb & 15;
  float s = powf(sigma[k], 0.25f) * (1.0f / 2048.0f);
  float2 v = mkf2(0.f, 0.f);
  if (f == 0) {
    float dc = Vf[(size_t)k * 1025].x;          // real
    float ny = Vf[(size_t)k * 1025 + 1024].x;   // real
    v = (kb < 16) ? mkf2(s * dc, s * ny) : mkf2(s * ny, s * dc);
  } else if (f <= 1023) {
    if (kb < 16) {
      v = Vf[(size_t)k * 1025 + f];
    } else {
      float2 t = Vf[(size_t)k * 1025 + (1024 - f)];
      v = mkf2(t.x, -t.y);
    }
    v.x *= s; v.y *= s;
  }
  cpcm[idx] = v;
}

// ---------------- merged: forward FFT (blocks 0..511) + weight cast (blocks 512..4287) --------
__global__ __launch_bounds__(256)
void k_fwdcast(const f16* __restrict__ hb2, f16* __restrict__ Xbf,
               const float2* __restrict__ tw,
               const float* __restrict__ mp, const float* __restrict__ mm,
               const float* __restrict__ mu, const float* __restrict__ fc1,
               const float* __restrict__ fc2,
               f16* __restrict__ Wsp, f16* __restrict__ Wu,
               f16* __restrict__ Wf1, f16* __restrict__ Wf2) {
  __shared__ __align__(16) char smem[16896];
  int wg = (int)blockIdx.x, tid = threadIdx.x;
  if (wg < 512) {
    // ---- forward FFT of hb2 -> Xbf; rows 0,1 = (DC.re, Nyq.re), rows 2f,2f+1 f=1..1023
    float2* z = (float2*)smem;
    int b = wg >> 8;
    int d0 = (wg & 255) * 2;
    for (int t = tid; t < 1024; t += 256) {
      union { unsigned v; f16 q[2]; } w;
      w.v = *(const unsigned*)(hb2 + (size_t)(b * 1026 + 2 + t) * 512 + d0);
      z[zp(t)] = mkf2((float)w.q[0], (float)w.q[1]);
    }
    for (int t = 1024 + tid; t < 2048; t += 256) z[zp(t)] = mkf2(0.f, 0.f);
    __syncthreads();
    fft2048<false>(z, tw, tid);
    for (int f = tid; f <= 1024; f += 256) {
      float2 zf = z[zp(f)], zc = z[zp((2048 - f) & 2047)];
      float x0r = 0.5f * (zf.x + zc.x), x0i = 0.5f * (zf.y - zc.y);
      float x1r = 0.5f * (zf.y + zc.y), x1i = 0.5f * (zc.x - zf.x);
      union { f16 h2[2]; unsigned u; } pr, pi;
      pr.h2[0] = (f16)x0r; pr.h2[1] = (f16)x1r;
      pi.h2[0] = (f16)x0i; pi.h2[1] = (f16)x1i;
      if (f == 0) {
        *(unsigned*)(Xbf + (size_t)(b * RPB) * 512 + d0) = pr.u;         // DC (im=0)
      } else if (f == 1024) {
        *(unsigned*)(Xbf + (size_t)(b * RPB + 1) * 512 + d0) = pr.u;     // Nyquist (im=0)
      } else {
        *(unsigned*)(Xbf + (size_t)(b * RPB + 2 * f) * 512 + d0)     = pr.u;
        *(unsigned*)(Xbf + (size_t)(b * RPB + 2 * f + 1) * 512 + d0) = pi.u;
      }
    }
    return;
  }
  // ---- weight cast/transpose, T[64][65] in smem
  float* T = (float*)smem;
  int blk = wg - 512;
  if (blk < 2048) {                    // Wsp: Wsp[(kb*512+o)][d] = m?[k][d][o]
    int mat = blk >> 6, tile = blk & 63;
    int d0 = (tile >> 3) * 64, o0 = (tile & 7) * 64;
    const float* src = (mat < 16) ? (mp + (size_t)mat * 262144)
                                  : (mm + (size_t)(mat - 16) * 262144);
    for (int q = tid; q < 4096; q += 256) {
      int i = q >> 6, j = q & 63;
      T[i * 65 + j] = src[(size_t)(d0 + i) * 512 + o0 + j];
    }
    __syncthreads();
    for (int q = tid; q < 4096; q += 256) {
      int i = q >> 6, j = q & 63;
      Wsp[(size_t)(mat * 512 + o0 + i) * 512 + d0 + j] = (f16)T[j * 65 + i];
    }
  } else if (blk < 2240) {             // Wu: Wu[o][ip*512+d] = mu[2-ip][d][o]
    int q0 = blk - 2048;
    int ip = q0 >> 6, tile = q0 & 63;
    int d0 = (tile >> 3) * 64, o0 = (tile & 7) * 64;
    const float* src = mu + (size_t)(2 - ip) * 262144;
    for (int q = tid; q < 4096; q += 256) {
      int i = q >> 6, j = q & 63;
      T[i * 65 + j] = src[(size_t)(d0 + i) * 512 + o0 + j];
    }
    __syncthreads();
    for (int q = tid; q < 4096; q += 256) {
      int i = q >> 6, j = q & 63;
      Wu[(size_t)(o0 + i) * 1536 + ip * 512 + d0 + j] = (f16)T[j * 65 + i];
    }
  } else if (blk < 3264) {             // fc1 perm copy: row 2h = y-row h, 2h+1 = gate-row h
    int q0 = blk - 2240;
    size_t e = ((size_t)q0 * 256 + tid) * 8;
    int jj = (int)(e >> 9), col = (int)(e & 511);
    int srow = (jj & 1) ? (2048 + (jj >> 1)) : (jj >> 1);
    const float4* s = (const float4*)(fc1 + (size_t)srow * 512 + col);
    float4 a = s[0], b = s[1];
    union { f16 h[8]; uint4 u; } pk;
    pk.h[0] = (f16)a.x; pk.h[1] = (f16)a.y; pk.h[2] = (f16)a.z; pk.h[3] = (f16)a.w;
    pk.h[4] = (f16)b.x; pk.h[5] = (f16)b.y; pk.h[6] = (f16)b.z; pk.h[7] = (f16)b.w;
    *(uint4*)(Wf1 + (size_t)jj * 512 + col) = pk.u;
  } else {                             // fc2 straight copy (already [o][j])
    int q0 = blk - 3264;
    size_t e = ((size_t)q0 * 256 + tid) * 8;
    const float4* s = (const float4*)(fc2 + e);
    float4 a = s[0], b = s[1];
    union { f16 h[8]; uint4 u; } pk;
    pk.h[0] = (f16)a.x; pk.h[1] = (f16)a.y; pk.h[2] = (f16)a.z; pk.h[3] = (f16)a.w;
    pk.h[4] = (f16)b.x; pk.h[5] = (f16)b.y; pk.h[6] = (f16)b.z; pk.h[7] = (f16)b.w;
    *(uint4*)(Wf2 + e) = pk.u;
  }
}

// ---------------- rmsnorm (f16 x in, zero-padded fp16 hb2 out) ----------------
__global__ void k_rmsnorm(const f16* __restrict__ x, const float* __restrict__ w,
                          f16* __restrict__ hb2) {
  int tid = threadIdx.x, l = tid & 63, wv = tid >> 6;
  int r = blockIdx.x * 4 + wv;
  int b = r >> 10, t = r & 1023;
  const f16* xr = x + (size_t)r * 512;
  f16* hr = hb2 + (size_t)(b * 1026 + 2 + t) * 512;
  float v[8]; float ss = 0.f;
#pragma unroll
  for (int j = 0; j < 8; ++j) { v[j] = (float)xr[j * 64 + l]; ss += v[j] * v[j]; }
#pragma unroll
  for (int o = 32; o; o >>= 1) ss += __shfl_xor(ss, o, 64);
  float rn = rsqrtf(ss * (1.f / 512.f) + 1e-5f);
#pragma unroll
  for (int j = 0; j < 8; ++j) {
    float hv = v[j] * rn * w[j * 64 + l];
    hr[j * 64 + l] = (f16)hv;
  }
}

// ---------------- inverse FFT: sum of NPART f16 partials -> spec f16 (512 blocks) ----------------
__global__ void k_fft_inv(const f16* __restrict__ P, f16* __restrict__ spec,
                          const float2* __restrict__ tw) {
  __shared__ float2 z[2112];
  int tid = threadIdx.x;
  int b = blockIdx.x >> 8;
  int o0 = (blockIdx.x & 255) * 2;
  for (int fp = tid; fp < 512; fp += 256) {
    int f0 = fp * 2;
    size_t base0 = (size_t)o0 * RTOT + (size_t)b * RPB + 2 * f0;
    float s0r[2] = {0.f, 0.f}, s0i[2] = {0.f, 0.f};
    float s1r[2] = {0.f, 0.f}, s1i[2] = {0.f, 0.f};
#pragma unroll
    for (int g = 0; g < NPART; ++g) {
      const f16* Pg = P + (size_t)g * 512 * RTOT;
      union { uint2 u; f16 h[4]; } ua, uc;
      ua.u = *(const uint2*)(Pg + base0);
      uc.u = *(const uint2*)(Pg + base0 + RTOT);
      s0r[0] += (float)ua.h[0]; s0i[0] += (float)ua.h[1];
      s0r[1] += (float)ua.h[2]; s0i[1] += (float)ua.h[3];
      s1r[0] += (float)uc.h[0]; s1i[0] += (float)uc.h[1];
      s1r[1] += (float)uc.h[2]; s1i[1] += (float)uc.h[3];
    }
    if (fp == 0) {
      z[zp(0)]    = mkf2(s0r[0], s1r[0]);   // DC of both real o-channels
      z[zp(1024)] = mkf2(s0i[0], s1i[0]);   // Nyquist of both
    } else {
      z[zp(f0)]        = mkf2(s0r[0] - s1i[0], s0i[0] + s1r[0]);
      z[zp(2048 - f0)] = mkf2(s0r[0] + s1i[0], s1r[0] - s0i[0]);
    }
    int f1 = f0 + 1;
    z[zp(f1)]        = mkf2(s0r[1] - s1i[1], s0i[1] + s1r[1]);
    z[zp(2048 - f1)] = mkf2(s0r[1] + s1i[1], s1r[1] - s0i[1]);
  }
  __syncthreads();
  fft2048<true>(z, tw, tid);
  for (int t = tid; t < 1024; t += 256) {
    float2 v = z[zp(t)];
    union { f16 h[2]; unsigned u; } pk;
    pk.h[0] = (f16)v.x; pk.h[1] = (f16)v.y;
    *(unsigned*)(spec + (size_t)(b * 1024 + t) * 512 + o0) = pk.u;
  }
}

// ---------------- gemm0: spectral GEMM, BK=128 (half the barriers of BK=64) ----------------
// Same 2-barrier single-buffer structure (proven best vs dbuf/vmcnt/unroll); 64KB LDS keeps
// 2 blocks/CU (unchanged — reg-capped anyway). 16x16x32 MFMA, swizzle generalized to 16 chunks.
__global__ __launch_bounds__(256, 2)
void k_gemm0(const f16* __restrict__ A, const f16* __restrict__ B0,
             const float* __restrict__ aux0, f16* __restrict__ outP) {
  __shared__ __align__(16) f16 As[128 * 128];
  __shared__ __align__(16) f16 Bs[128 * 128];
  const int tid = threadIdx.x, l = tid & 63, wvi = tid >> 6;
  const int wr = wvi >> 1, wc = wvi & 1;
  int wg = (int)blockIdx.x;            // 512 = 8 * 64, bijective XCD chunk swizzle
  wg = (wg & 7) * 64 + (wg >> 3);
  const int bz = wg >> 7; int rem = wg & 127;
  const int by = rem >> 2, bx = rem & 3;
  const int r0 = by * 128, c0 = bx * 128;

  f32x4 acc[4][4];
  f32x4 crun[4][4];
  f32x4 zz = {0.f, 0.f, 0.f, 0.f};
#pragma unroll
  for (int m = 0; m < 4; ++m)
#pragma unroll
    for (int n = 0; n < 4; ++n) { acc[m][n] = zz; crun[m][n] = zz; }

  const int rowl = tid >> 4;                        // 0..15
  const int lc8 = ((tid & 15) ^ (rowl & 7)) * 8;    // swizzled chunk*8 (16 chunks of 8 f16)
  f16* lA = As + ((tid >> 6) << 9);                 // wave base: 4 rows x 128 f16
  f16* lB = Bs + ((tid >> 6) << 9);
  const int lr = l & 15, kg = l >> 4, sw = l & 7;

  for (int s = 0; s < 32; ++s) {
    __syncthreads();                   // prior mma's LDS reads done
    {
      const int dblk = (s & 3) * 128;
      const int kb = bz * 8 + (s >> 2);
      const f16* Ab = A + (size_t)(r0 + rowl) * 512 + dblk + lc8;
      const f16* Bb = B0 + (size_t)(kb * 512 + c0 + rowl) * 512 + dblk + lc8;
#pragma unroll
      for (int i = 0; i < 8; ++i) {
        gl16(Ab + (size_t)i * 16 * 512, lA + i * 2048);
        gl16(Bb + (size_t)i * 16 * 512, lB + i * 2048);
      }
    }
    __syncthreads();                   // staging landed (compiler drains vmcnt)
#pragma unroll
    for (int kk = 0; kk < 4; ++kk) {
      half8 af[4], bf[4];
      const int pc8 = (((kk * 4 + kg) ^ sw) << 3);
#pragma unroll
      for (int m = 0; m < 4; ++m)
        af[m] = *(const half8*)(As + (wr * 64 + m * 16 + lr) * 128 + pc8);
#pragma unroll
      for (int n = 0; n < 4; ++n)
        bf[n] = *(const half8*)(Bs + (wc * 64 + n * 16 + lr) * 128 + pc8);
#pragma unroll
      for (int m = 0; m < 4; ++m)
#pragma unroll
        for (int n = 0; n < 4; ++n)
          acc[m][n] = __builtin_amdgcn_mfma_f32_16x16x32_f16(af[m], bf[n], acc[m][n], 0, 0, 0);
    }
    if ((s & 3) == 3) {                // per-kb complex rescale into running sum
      int kb = bz * 8 + (s >> 2);
#pragma unroll
      for (int m = 0; m < 4; ++m) {
        int R = r0 + wr * 64 + m * 16 + (kg << 2);
        int rb = R & (RPB - 1);
        bool dc = (rb == 0);           // rows 0,1 = packed (DC.re, Nyq.re): scale separately
        float4 cs = *(const float4*)(aux0 + (size_t)kb * (CPS * 2) + (rb >> 1) * 2);
        float t1 = dc ? 0.f : cs.y;
        float t2 = dc ? cs.y : cs.x;
#pragma unroll
        for (int n = 0; n < 4; ++n) {
          f32x4 p = acc[m][n];
          crun[m][n].x += cs.x * p.x - t1 * p.y;
          crun[m][n].y += t2 * p.y + t1 * p.x;
          crun[m][n].z += cs.z * p.z - cs.w * p.w;
          crun[m][n].w += cs.z * p.w + cs.w * p.z;
          acc[m][n] = zz;
        }
      }
    }
  }

  f16* P = outP + (size_t)bz * (512ull * RTOT);
#pragma unroll
  for (int m = 0; m < 4; ++m) {
    int R0 = r0 + wr * 64 + m * 16 + (kg << 2);
#pragma unroll
    for (int n = 0; n < 4; ++n) {
      int o = c0 + wc * 64 + n * 16 + lr;
      union { f16 h[4]; uint2 u; } pk;
      pk.h[0] = (f16)crun[m][n].x; pk.h[1] = (f16)crun[m][n].y;
      pk.h[2] = (f16)crun[m][n].z; pk.h[3] = (f16)crun[m][n].w;
      *(uint2*)(P + (size_t)o * RTOT + R0) = pk.u;
    }
  }
}

// ---------------- generic MFMA GEMM (modes 1-3, BK=64, round-2 structure) ----------
template<int MODE, int MR, int NR>
__device__ __forceinline__ void stage(const f16* __restrict__ A, const f16* __restrict__ B0,
                                      int r0, int c0, int tid, int s,
                                      f16* As, f16* Bs) {
  constexpr int LDA = (MODE == 1) ? 1536 : (MODE == 2) ? 512 : 2048;
  const int kA = s * 64;
  const int rowl = tid >> 3;
  const int lc8 = ((tid & 7) ^ (rowl & 7)) * 8;   // swizzled chunk * 8 (f16)
  f16* lA = As + ((tid >> 6) << 9);               // wave-uniform LDS base
  f16* lB = Bs + ((tid >> 6) << 9);
#pragma unroll
  for (int i = 0; i < MR; ++i) {
    int row = i * 32 + rowl;
    gl16(A + (size_t)(r0 + row) * LDA + kA + lc8, lA + i * 2048);
  }
#pragma unroll
  for (int i = 0; i < NR; ++i) {
    int row = i * 32 + rowl;
    const f16* bs;
    if constexpr (MODE == 1) {
      int ip = s >> 3, d0 = (s & 7) * 64;
      int rr = c0 + row;
      int b = rr >> 10, t = rr & 1023;
      bs = B0 + (size_t)(b * 1026 + t + ip) * 512 + d0 + lc8;   // pad rows are zero
    } else {
      constexpr int LDB = (MODE == 2) ? 512 : 2048;
      bs = B0 + (size_t)(c0 + row) * LDB + s * 64 + lc8;
    }
    gl16(bs, lB + i * 2048);
  }
}

template<int MR, int NR>
__device__ __forceinline__ void mma_step(const f16* As, const f16* Bs, int l, int wr, int wc,
                                         f32x4 acc[MR][NR]) {
  const int lr = l & 15, kg = l >> 4, sw = l & 7;
#pragma unroll
  for (int kk = 0; kk < 2; ++kk) {
    half8 af[MR], bf[NR];
    const int pc8 = (((kk * 4 + kg) ^ sw) << 3);
#pragma unroll
    for (int m = 0; m < MR; ++m)
      af[m] = *(const half8*)(As + (wr * (MR * 16) + m * 16 + lr) * 64 + pc8);
#pragma unroll
    for (int n = 0; n < NR; ++n)
      bf[n] = *(const half8*)(Bs + (wc * (NR * 16) + n * 16 + lr) * 64 + pc8);
#pragma unroll
    for (int m = 0; m < MR; ++m)
#pragma unroll
      for (int n = 0; n < NR; ++n)
        acc[m][n] = __builtin_amdgcn_mfma_f32_16x16x32_f16(af[m], bf[n], acc[m][n], 0, 0, 0);
  }
}

template<int MODE, int MR, int NR>
__global__ __launch_bounds__(256, (MODE == 2) ? 3 : 4)
void k_gemm(const f16* __restrict__ A, const f16* __restrict__ B0,
            const f16* auxA, const f16* auxB, f16* __restrict__ outH) {
  __shared__ __align__(16) f16 As[MR * 32 * 64];
  __shared__ __align__(16) f16 Bs[NR * 32 * 64];
  const int tid = threadIdx.x, l = tid & 63, wvi = tid >> 6;
  const int wr = wvi >> 1, wc = wvi & 1;
  const int bx = blockIdx.x, by = blockIdx.y;
  const int r0 = by * (MR * 32), c0 = bx * (NR * 32);
  constexpr int KS = (MODE == 1) ? 24 : (MODE == 2) ? 8 : 32;

  f32x4 acc[MR][NR];
  f32x4 zz = {0.f, 0.f, 0.f, 0.f};
#pragma unroll
  for (int m = 0; m < MR; ++m)
#pragma unroll
    for (int n = 0; n < NR; ++n) acc[m][n] = zz;

  for (int s = 0; s < KS; ++s) {
    __syncthreads();
    stage<MODE, MR, NR>(A, B0, r0, c0, tid, s, As, Bs);
    __syncthreads();
    mma_step<MR, NR>(As, Bs, l, wr, wc, acc);
  }

  if constexpr (MODE == 1) {
#pragma unroll
    for (int m = 0; m < MR; ++m) {
      int o0 = r0 + wr * (MR * 16) + m * 16 + ((l >> 4) << 2);
#pragma unroll
      for (int n = 0; n < NR; ++n) {
        int r = c0 + wc * (NR * 16) + n * 16 + (l & 15);
        union { uint2 u; f16 h[4]; } xv, sv;
        xv.u = *(const uint2*)(auxA + (size_t)r * 512 + o0);
        sv.u = *(const uint2*)(auxB + (size_t)r * 512 + o0);
        f32x4 a = acc[m][n];
        union { f16 h[4]; uint2 u; } pk;
        pk.h[0] = (f16)((float)xv.h[0] + (float)sv.h[0] + a.x);
        pk.h[1] = (f16)((float)xv.h[1] + (float)sv.h[1] + a.y);
        pk.h[2] = (f16)((float)xv.h[2] + (float)sv.h[2] + a.z);
        pk.h[3] = (f16)((float)xv.h[3] + (float)sv.h[3] + a.w);
        *(uint2*)(outH + (size_t)r * 512 + o0) = pk.u;
      }
    }
  } else if constexpr (MODE == 2) {
#pragma unroll
    for (int m = 0; m < MR; ++m) {
      int jj0 = r0 + wr * (MR * 16) + m * 16 + ((l >> 4) << 2);
      int h2 = jj0 >> 1;
#pragma unroll
      for (int n = 0; n < NR; ++n) {
        int r = c0 + wc * (NR * 16) + n * 16 + (l & 15);
        f32x4 a = acc[m][n];
        float v0 = a.x * (a.y / (1.f + __expf(-a.y)));
        float v1 = a.z * (a.w / (1.f + __expf(-a.w)));
        union { f16 h[2]; unsigned u; } pk;
        pk.h[0] = (f16)v0; pk.h[1] = (f16)v1;
        *(unsigned*)(outH + (size_t)r * 2048 + h2) = pk.u;
      }
    }
  } else {
#pragma unroll
    for (int m = 0; m < MR; ++m) {
      int o0 = r0 + wr * (MR * 16) + m * 16 + ((l >> 4) << 2);
#pragma unroll
      for (int n = 0; n < NR; ++n) {
        int r = c0 + wc * (NR * 16) + n * 16 + (l & 15);
        union { uint2 u; f16 h[4]; } xv, x1v;
        xv.u  = *(const uint2*)(auxA + (size_t)r * 512 + o0);
        x1v.u = *(const uint2*)(auxB + (size_t)r * 512 + o0);
        f32x4 a = acc[m][n];
        union { f16 h[4]; uint2 u; } pk;
        pk.h[0] = (f16)((float)xv.h[0] + (float)x1v.h[0] + a.x);
        pk.h[1] = (f16)((float)xv.h[1] + (float)x1v.h[1] + a.y);
        pk.h[2] = (f16)((float)xv.h[2] + (float)x1v.h[2] + a.z);
        pk.h[3] = (f16)((float)xv.h[3] + (float)x1v.h[3] + a.w);
        *(uint2*)(outH + (size_t)r * 512 + o0) = pk.u;
      }
    }
  }
}

// ---------------- small projections ----------------
__global__ void k_inproj(const float* __restrict__ inp, const float* __restrict__ W,
                         f16* __restrict__ x) {
  __shared__ float row[64];
  int r = blockIdx.x, tid = threadIdx.x;
  if (tid < 64) row[tid] = inp[(size_t)r * 64 + tid];
  __syncthreads();
  for (int o = tid; o < 512; o += 256) {
    const float* wr = W + (size_t)o * 64;
    float acc = 0.f;
#pragma unroll 8
    for (int q = 0; q < 64; ++q) acc += row[q] * wr[q];
    x[(size_t)r * 512 + o] = (f16)acc;
  }
}

__global__ void k_outproj(const f16* __restrict__ x, const float* __restrict__ W,
                          float* out, int add) {
  __shared__ float row[512];
  int r = blockIdx.x, tid = threadIdx.x;
  for (int i = tid; i < 512; i += 256) row[i] = (float)x[(size_t)r * 512 + i];
  __syncthreads();
  int o = tid >> 2, part = tid & 3;
  const float* wr = W + (size_t)o * 512 + part * 128;
  const float* rp = row + part * 128;
  float acc = 0.f;
#pragma unroll 16
  for (int q = 0; q < 128; ++q) acc += rp[q] * wr[q];
  acc += __shfl_xor(acc, 1, 64);
  acc += __shfl_xor(acc, 2, 64);
  if (part == 0) {
    if (add) out[(size_t)r * 64 + o] += acc;
    else     out[(size_t)r * 64 + o] = acc;
  }
}

// ---------------- host ----------------
extern "C" void kernel_launch(void* const* d_in, const int* in_sizes, int n_in,
                              void* d_out, int out_size, void* d_ws, size_t ws_size,
                              hipStream_t stream) {
  const float* inputs    = (const float*)d_in[0];
  const float* sigma     = (const float*)d_in[1];
  const float* phi       = (const float*)d_in[2];
  const float* in_proj_w = (const float*)d_in[3];
  const float* rn_w      = (const float*)d_in[4];
  const float* M_u       = (const float*)d_in[5];
  const float* M_phi_p   = (const float*)d_in[6];
  const float* M_phi_m   = (const float*)d_in[7];
  const float* fc1       = (const float*)d_in[8];
  const float* fc2       = (const float*)d_in[9];
  const float* out_proj_w= (const float*)d_in[10];
  float* out = (float*)d_out;

  char* ws = (char*)d_ws;
  size_t off = 0;
  auto alloc = [&](size_t bytes) -> void* {
    void* p = ws + off;
    off += (bytes + 255) & ~(size_t)255;
    return p;
  };
  float2* tw   = (float2*)alloc(1024 * 8);
  float2* Vf   = (float2*)alloc((size_t)16 * 1025 * 8);
  float2* cpcm = (float2*)alloc((size_t)32 * CPS * 8);
  f16*    x    = (f16*)alloc((size_t)NROW * 512 * 2);
  f16*    hb2  = (f16*)alloc((size_t)2052 * 512 * 2);   // 2 batches x (2 pad + 1024) rows
  f16*    x1   = (f16*)alloc((size_t)NROW * 512 * 2);
  f16*    spec = (f16*)alloc((size_t)NROW * 512 * 2);
  f16*    Xbf  = (f16*)alloc((size_t)RTOT * 512 * 2);
  f16*    P    = (f16*)alloc((size_t)NPART * 512 * RTOT * 2);
  f16*    g1   = (f16*)alloc((size_t)NROW * 2048 * 2);
  f16*    Wsp  = (f16*)alloc((size_t)16384 * 512 * 2);
  f16*    Wu   = (f16*)alloc((size_t)512 * 1536 * 2);
  f16*    Wf1  = (f16*)alloc((size_t)4096 * 512 * 2);
  f16*    Wf2  = (f16*)alloc((size_t)512 * 2048 * 2);
  if (off > ws_size) return;  // workspace too small: fail loudly (output stays poisoned)

  // zero the AR window pad rows (rows 0,1 of each batch block in hb2)
  hipMemsetAsync(hb2, 0, 2 * 512 * sizeof(f16), stream);
  hipMemsetAsync(hb2 + (size_t)1026 * 512, 0, 2 * 512 * sizeof(f16), stream);
  k_twiddle<<<4, 256, 0, stream>>>(tw);
  k_fft_phi<<<8, 256, 0, stream>>>(phi, Vf, tw);
  k_cpcm<<<133, 256, 0, stream>>>(Vf, sigma, cpcm);

  for (int m = 0; m < 2; ++m) {
    k_inproj<<<NROW, 256, 0, stream>>>(inputs, in_proj_w + (size_t)m * 512 * 64, x);
    for (int li = 0; li < 2; ++li) {
      int ml = m * 2 + li;
      k_rmsnorm<<<512, 256, 0, stream>>>(x, rn_w + (size_t)ml * 512, hb2);
      k_fwdcast<<<512 + 3776, 256, 0, stream>>>(
          hb2, Xbf, tw,
          M_phi_p + (size_t)ml * 16 * 262144, M_phi_m + (size_t)ml * 16 * 262144,
          M_u + (size_t)ml * 3 * 262144, fc1 + (size_t)ml * 4096 * 512,
          fc2 + (size_t)ml * 512 * 2048, Wsp, Wu, Wf1, Wf2);
      k_gemm0<<<dim3(512), 256, 0, stream>>>(Xbf, Wsp, (const float*)cpcm, P);
      k_fft_inv<<<512, 256, 0, stream>>>(P, spec, tw);
      k_gemm<1, 2, 2><<<dim3(32, 8), 256, 0, stream>>>(Wu, hb2, x, spec, x1);
      k_gemm<2, 4, 4><<<dim3(16, 32), 256, 0, stream>>>(Wf1, x1, nullptr, nullptr, g1);
      k_gemm<3, 2, 2><<<dim3(32, 8), 256, 0, stream>>>(Wf2, g1, x, x1, x);
    }
    k_outproj<<<NROW, 256, 0, stream>>>(x, out_proj_w + (size_t)m * 64 * 512, out, m);
  }
}

// Round 14
// 781.673 us; speedup vs baseline: 1.0597x; 1.0597x over previous
//
#include <hip/hip_runtime.h>
#include <hip/hip_bf16.h>

typedef _Float16 f16;
typedef _Float16 half8 __attribute__((ext_vector_type(8)));
typedef float f32x4 __attribute__((ext_vector_type(4)));

#define S_LEN 1024
#define DMODEL 512
#define NFFT   2048
#define RPB    2048     // rows per batch: f=1..1023 pairs + packed (DC.re, Nyq.re) in rows 0,1
#define RTOT   4096     // per-model: 2 batches -> exactly 32 row-tiles of 128
#define CPS    1064     // cpcm f-stride
#define NROW   2048     // B*S per model
#define NPART  4        // split-K partials for spectral GEMM

__device__ __forceinline__ float2 mkf2(float a, float b) { float2 r; r.x = a; r.y = b; return r; }
__device__ __forceinline__ int zp(int i) { return i + (i >> 5); }   // LDS bank-pad for FFT array
__device__ __forceinline__ float2 cmul(float2 w, float2 b) {
  return mkf2(b.x * w.x - b.y * w.y, b.x * w.y + b.y * w.x);
}
__device__ __forceinline__ float2 f2a(float2 a, float2 b) { return mkf2(a.x + b.x, a.y + b.y); }
__device__ __forceinline__ float2 f2s(float2 a, float2 b) { return mkf2(a.x - b.x, a.y - b.y); }

// async global->LDS (16B per lane). LDS dest must be wave-uniform base; lane writes at +lane*16.
__device__ __forceinline__ void gl16(const f16* g, f16* l) {
  __builtin_amdgcn_global_load_lds((const __attribute__((address_space(1))) void*)g,
                                   (__attribute__((address_space(3))) void*)l, 16, 0, 0);
}

// ---------------- FFT-2048 in LDS: 3x radix-8 + 1x radix-4, padded indexing ----------------
template<bool INV>
__device__ __forceinline__ void fft2048(float2* z, const float2* __restrict__ tw, int tid) {
  for (int i = tid; i < 2048; i += 256) {
    int j = (int)(__brev((unsigned)i) >> 21);
    if (i < j) { float2 a = z[zp(i)]; z[zp(i)] = z[zp(j)]; z[zp(j)] = a; }
  }
  __syncthreads();
#pragma unroll
  for (int r8 = 0; r8 < 3; ++r8) {       // fused stages (1,2,3),(4,5,6),(7,8,9)
    const int sl = 1 + 3 * r8;
    const int h = 1 << (sl - 1);
    {
      int q = tid;                        // 256 groups of 8, one per thread
      int j = q & (h - 1);
      int i0 = ((q >> (sl - 1)) << (sl + 2)) + j;
      float2 a0 = z[zp(i0)],         a1 = z[zp(i0 + h)];
      float2 a2 = z[zp(i0 + 2 * h)], a3 = z[zp(i0 + 3 * h)];
      float2 a4 = z[zp(i0 + 4 * h)], a5 = z[zp(i0 + 5 * h)];
      float2 a6 = z[zp(i0 + 6 * h)], a7 = z[zp(i0 + 7 * h)];
      float2 wA  = tw[j << (11 - sl)];
      float2 wB0 = tw[j << (10 - sl)];
      float2 wB1 = tw[(j + h) << (10 - sl)];
      float2 wC0 = tw[j << (9 - sl)];
      float2 wC1 = tw[(j + h) << (9 - sl)];
      float2 wC2 = tw[(j + 2 * h) << (9 - sl)];
      float2 wC3 = tw[(j + 3 * h) << (9 - sl)];
      if (INV) {
        wA.y = -wA.y; wB0.y = -wB0.y; wB1.y = -wB1.y;
        wC0.y = -wC0.y; wC1.y = -wC1.y; wC2.y = -wC2.y; wC3.y = -wC3.y;
      }
      float2 t;
      t = cmul(wA, a1); float2 b0 = f2a(a0, t), b1 = f2s(a0, t);
      t = cmul(wA, a3); float2 b2 = f2a(a2, t), b3 = f2s(a2, t);
      t = cmul(wA, a5); float2 b4 = f2a(a4, t), b5 = f2s(a4, t);
      t = cmul(wA, a7); float2 b6 = f2a(a6, t), b7 = f2s(a6, t);
      t = cmul(wB0, b2); float2 c0 = f2a(b0, t), c2 = f2s(b0, t);
      t = cmul(wB1, b3); float2 c1 = f2a(b1, t), c3 = f2s(b1, t);
      t = cmul(wB0, b6); float2 c4 = f2a(b4, t), c6 = f2s(b4, t);
      t = cmul(wB1, b7); float2 c5 = f2a(b5, t), c7 = f2s(b5, t);
      t = cmul(wC0, c4); z[zp(i0)]         = f2a(c0, t); z[zp(i0 + 4 * h)] = f2s(c0, t);
      t = cmul(wC1, c5); z[zp(i0 + h)]     = f2a(c1, t); z[zp(i0 + 5 * h)] = f2s(c1, t);
      t = cmul(wC2, c6); z[zp(i0 + 2 * h)] = f2a(c2, t); z[zp(i0 + 6 * h)] = f2s(c2, t);
      t = cmul(wC3, c7); z[zp(i0 + 3 * h)] = f2a(c3, t); z[zp(i0 + 7 * h)] = f2s(c3, t);
    }
    __syncthreads();
  }
  for (int q = tid; q < 512; q += 256) {  // final radix-4 round: stages (10,11)
    float2 a0 = z[zp(q)], a1 = z[zp(q + 512)], a2 = z[zp(q + 1024)], a3 = z[zp(q + 1536)];
    float2 w1 = tw[q << 1], w2 = tw[q], w3 = tw[q + 512];
    if (INV) { w1.y = -w1.y; w2.y = -w2.y; w3.y = -w3.y; }
    float2 t;
    t = cmul(w1, a1); float2 b0 = f2a(a0, t), b1 = f2s(a0, t);
    t = cmul(w1, a3); float2 b2 = f2a(a2, t), b3 = f2s(a2, t);
    t = cmul(w2, b2); z[zp(q)]        = f2a(b0, t); z[zp(q + 1024)] = f2s(b0, t);
    t = cmul(w3, b3); z[zp(q + 512)]  = f2a(b1, t); z[zp(q + 1536)] = f2s(b1, t);
  }
  __syncthreads();
}

// ---------------- init kernels ----------------
__global__ void k_twiddle(float2* tw) {
  int i = blockIdx.x * 256 + threadIdx.x;
  if (i < 1024) {
    float ang = -6.2831853071795864769f * (float)i / 2048.0f;
    tw[i] = mkf2(cosf(ang), sinf(ang));
  }
}

// rfft of phi columns (pairs packed into one complex FFT)
__global__ void k_fft_phi(const float* __restrict__ phi, float2* __restrict__ Vf,
                          const float2* __restrict__ tw) {
  __shared__ float2 z[2112];
  int tid = threadIdx.x;
  int k0 = blockIdx.x * 2;
  for (int t = tid; t < 1024; t += 256)
    z[zp(t)] = *(const float2*)(phi + (size_t)t * 16 + k0);
  for (int t = 1024 + tid; t < 2048; t += 256) z[zp(t)] = mkf2(0.f, 0.f);
  __syncthreads();
  fft2048<false>(z, tw, tid);
  for (int f = tid; f <= 1024; f += 256) {
    float2 zf = z[zp(f)], zc = z[zp((2048 - f) & 2047)];
    Vf[(size_t)k0 * 1025 + f]       = mkf2(0.5f * (zf.x + zc.x), 0.5f * (zf.y - zc.y));
    Vf[(size_t)(k0 + 1) * 1025 + f] = mkf2(0.5f * (zf.y + zc.y), 0.5f * (zc.x - zf.x));
  }
}

// cpcm[kb][f]: f=1..1023 standard complex scale; slot 0 packs (c_DC, c_Nyq) (both REAL).
__global__ void k_cpcm(const float2* __restrict__ Vf, const float* __restrict__ sigma,
                       float2* __restrict__ cpcm) {
  int idx = blockIdx.x * 256 + threadIdx.x;
  if (idx >= 32 * CPS) return;
  int kb = idx / CPS, f = idx - kb * CPS;
  int k = kb & 15;
  float s = powf(sigma[k], 0.25f) * (1.0f / 2048.0f);
  float2 v = mkf2(0.f, 0.f);
  if (f == 0) {
    float dc = Vf[(size_t)k * 1025].x;          // real
    float ny = Vf[(size_t)k * 1025 + 1024].x;   // real
    v = (kb < 16) ? mkf2(s * dc, s * ny) : mkf2(s * ny, s * dc);
  } else if (f <= 1023) {
    if (kb < 16) {
      v = Vf[(size_t)k * 1025 + f];
    } else {
      float2 t = Vf[(size_t)k * 1025 + (1024 - f)];
      v = mkf2(t.x, -t.y);
    }
    v.x *= s; v.y *= s;
  }
  cpcm[idx] = v;
}

// ---------------- merged per-layer: fwd FFT both models (0..1023) + cast both models ----------
__global__ __launch_bounds__(256)
void k_fwdcast(const f16* __restrict__ hb2, f16* __restrict__ Xbf,
               const float2* __restrict__ tw, int li,
               const float* __restrict__ Mp, const float* __restrict__ Mm,
               const float* __restrict__ Mu, const float* __restrict__ Fc1,
               const float* __restrict__ Fc2,
               f16* __restrict__ Wsp, f16* __restrict__ Wu,
               f16* __restrict__ Wf1, f16* __restrict__ Wf2) {
  __shared__ __align__(16) char smem[16896];
  int wg = (int)blockIdx.x, tid = threadIdx.x;
  if (wg < 1024) {
    // ---- forward FFT of hb2 -> Xbf; rows 0,1 = (DC.re, Nyq.re), rows 2f,2f+1 f=1..1023
    float2* z = (float2*)smem;
    int model = wg >> 9;
    int b = (wg >> 8) & 1;
    int d0 = (wg & 255) * 2;
    const f16* hsrc = hb2 + (size_t)(model * 2 + b) * 1026 * 512;
    f16* xdst = Xbf + (size_t)model * RTOT * 512 + (size_t)b * RPB * 512;
    for (int t = tid; t < 1024; t += 256) {
      union { unsigned v; f16 q[2]; } w;
      w.v = *(const unsigned*)(hsrc + (size_t)(2 + t) * 512 + d0);
      z[zp(t)] = mkf2((float)w.q[0], (float)w.q[1]);
    }
    for (int t = 1024 + tid; t < 2048; t += 256) z[zp(t)] = mkf2(0.f, 0.f);
    __syncthreads();
    fft2048<false>(z, tw, tid);
    for (int f = tid; f <= 1024; f += 256) {
      float2 zf = z[zp(f)], zc = z[zp((2048 - f) & 2047)];
      float x0r = 0.5f * (zf.x + zc.x), x0i = 0.5f * (zf.y - zc.y);
      float x1r = 0.5f * (zf.y + zc.y), x1i = 0.5f * (zc.x - zf.x);
      union { f16 h2[2]; unsigned u; } pr, pi;
      pr.h2[0] = (f16)x0r; pr.h2[1] = (f16)x1r;
      pi.h2[0] = (f16)x0i; pi.h2[1] = (f16)x1i;
      if (f == 0) {
        *(unsigned*)(xdst + d0) = pr.u;                                  // DC (im=0)
      } else if (f == 1024) {
        *(unsigned*)(xdst + (size_t)512 + d0) = pr.u;                    // Nyquist (im=0)
      } else {
        *(unsigned*)(xdst + (size_t)(2 * f) * 512 + d0)     = pr.u;
        *(unsigned*)(xdst + (size_t)(2 * f + 1) * 512 + d0) = pi.u;
      }
    }
    return;
  }
  // ---- weight cast/transpose for BOTH models (interleaved by low bit), T[64][65] in smem
  float* T = (float*)smem;
  int q0all = wg - 1024;               // 0..7551
  int model = q0all & 1;
  int blk = q0all >> 1;                // 0..3775
  int ml = model * 2 + li;
  const float* mp  = Mp  + (size_t)ml * 16 * 262144;
  const float* mm  = Mm  + (size_t)ml * 16 * 262144;
  const float* mu  = Mu  + (size_t)ml * 3 * 262144;
  const float* fc1 = Fc1 + (size_t)ml * 4096 * 512;
  const float* fc2 = Fc2 + (size_t)ml * 512 * 2048;
  f16* WspM = Wsp + (size_t)model * 16384 * 512;
  f16* WuM  = Wu  + (size_t)model * 512 * 1536;
  f16* Wf1M = Wf1 + (size_t)model * 4096 * 512;
  f16* Wf2M = Wf2 + (size_t)model * 512 * 2048;
  if (blk < 2048) {                    // Wsp: Wsp[(kb*512+o)][d] = m?[k][d][o]
    int mat = blk >> 6, tile = blk & 63;
    int d0 = (tile >> 3) * 64, o0 = (tile & 7) * 64;
    const float* src = (mat < 16) ? (mp + (size_t)mat * 262144)
                                  : (mm + (size_t)(mat - 16) * 262144);
    for (int q = tid; q < 4096; q += 256) {
      int i = q >> 6, j = q & 63;
      T[i * 65 + j] = src[(size_t)(d0 + i) * 512 + o0 + j];
    }
    __syncthreads();
    for (int q = tid; q < 4096; q += 256) {
      int i = q >> 6, j = q & 63;
      WspM[(size_t)(mat * 512 + o0 + i) * 512 + d0 + j] = (f16)T[j * 65 + i];
    }
  } else if (blk < 2240) {             // Wu: Wu[o][ip*512+d] = mu[2-ip][d][o]
    int q1 = blk - 2048;
    int ip = q1 >> 6, tile = q1 & 63;
    int d0 = (tile >> 3) * 64, o0 = (tile & 7) * 64;
    const float* src = mu + (size_t)(2 - ip) * 262144;
    for (int q = tid; q < 4096; q += 256) {
      int i = q >> 6, j = q & 63;
      T[i * 65 + j] = src[(size_t)(d0 + i) * 512 + o0 + j];
    }
    __syncthreads();
    for (int q = tid; q < 4096; q += 256) {
      int i = q >> 6, j = q & 63;
      WuM[(size_t)(o0 + i) * 1536 + ip * 512 + d0 + j] = (f16)T[j * 65 + i];
    }
  } else if (blk < 3264) {             // fc1 perm copy: row 2h = y-row h, 2h+1 = gate-row h
    int q1 = blk - 2240;
    size_t e = ((size_t)q1 * 256 + tid) * 8;
    int jj = (int)(e >> 9), col = (int)(e & 511);
    int srow = (jj & 1) ? (2048 + (jj >> 1)) : (jj >> 1);
    const float4* s = (const float4*)(fc1 + (size_t)srow * 512 + col);
    float4 a = s[0], b = s[1];
    union { f16 h[8]; uint4 u; } pk;
    pk.h[0] = (f16)a.x; pk.h[1] = (f16)a.y; pk.h[2] = (f16)a.z; pk.h[3] = (f16)a.w;
    pk.h[4] = (f16)b.x; pk.h[5] = (f16)b.y; pk.h[6] = (f16)b.z; pk.h[7] = (f16)b.w;
    *(uint4*)(Wf1M + (size_t)jj * 512 + col) = pk.u;
  } else {                             // fc2 straight copy (already [o][j])
    int q1 = blk - 3264;
    size_t e = ((size_t)q1 * 256 + tid) * 8;
    const float4* s = (const float4*)(fc2 + e);
    float4 a = s[0], b = s[1];
    union { f16 h[8]; uint4 u; } pk;
    pk.h[0] = (f16)a.x; pk.h[1] = (f16)a.y; pk.h[2] = (f16)a.z; pk.h[3] = (f16)a.w;
    pk.h[4] = (f16)b.x; pk.h[5] = (f16)b.y; pk.h[6] = (f16)b.z; pk.h[7] = (f16)b.w;
    *(uint4*)(Wf2M + e) = pk.u;
  }
}

// ---------------- rmsnorm both models (grid 1024) ----------------
__global__ void k_rmsnorm(const f16* __restrict__ x, const float* __restrict__ rn_w, int li,
                          f16* __restrict__ hb2) {
  int tid = threadIdx.x, l = tid & 63, wv = tid >> 6;
  int r = blockIdx.x * 4 + wv;           // 0..4095 global row
  int model = r >> 11;
  int rl = r & 2047;
  int b = rl >> 10, t = rl & 1023;
  const float* w = rn_w + (size_t)(model * 2 + li) * 512;
  const f16* xr = x + (size_t)r * 512;
  f16* hr = hb2 + (size_t)((model * 2 + b) * 1026 + 2 + t) * 512;
  float v[8]; float ss = 0.f;
#pragma unroll
  for (int j = 0; j < 8; ++j) { v[j] = (float)xr[j * 64 + l]; ss += v[j] * v[j]; }
#pragma unroll
  for (int o = 32; o; o >>= 1) ss += __shfl_xor(ss, o, 64);
  float rn = rsqrtf(ss * (1.f / 512.f) + 1e-5f);
#pragma unroll
  for (int j = 0; j < 8; ++j) {
    float hv = v[j] * rn * w[j * 64 + l];
    hr[j * 64 + l] = (f16)hv;
  }
}

// ---------------- inverse FFT both models: sum NPART partials -> spec f16 (grid 1024) --------
__global__ void k_fft_inv(const f16* __restrict__ P, f16* __restrict__ spec,
                          const float2* __restrict__ tw) {
  __shared__ float2 z[2112];
  int tid = threadIdx.x;
  int wg = (int)blockIdx.x;
  int model = wg >> 9;
  int b = (wg >> 8) & 1;
  int o0 = (wg & 255) * 2;
  const f16* Pm = P + (size_t)model * 512 * RTOT;
  for (int fp = tid; fp < 512; fp += 256) {
    int f0 = fp * 2;
    size_t base0 = (size_t)o0 * RTOT + (size_t)b * RPB + 2 * f0;
    float s0r[2] = {0.f, 0.f}, s0i[2] = {0.f, 0.f};
    float s1r[2] = {0.f, 0.f}, s1i[2] = {0.f, 0.f};
#pragma unroll
    for (int g = 0; g < NPART; ++g) {
      const f16* Pg = Pm + (size_t)g * (2ull * 512 * RTOT);
      union { uint2 u; f16 h[4]; } ua, uc;
      ua.u = *(const uint2*)(Pg + base0);
      uc.u = *(const uint2*)(Pg + base0 + RTOT);
      s0r[0] += (float)ua.h[0]; s0i[0] += (float)ua.h[1];
      s0r[1] += (float)ua.h[2]; s0i[1] += (float)ua.h[3];
      s1r[0] += (float)uc.h[0]; s1i[0] += (float)uc.h[1];
      s1r[1] += (float)uc.h[2]; s1i[1] += (float)uc.h[3];
    }
    if (fp == 0) {
      z[zp(0)]    = mkf2(s0r[0], s1r[0]);   // DC of both real o-channels
      z[zp(1024)] = mkf2(s0i[0], s1i[0]);   // Nyquist of both
    } else {
      z[zp(f0)]        = mkf2(s0r[0] - s1i[0], s0i[0] + s1r[0]);
      z[zp(2048 - f0)] = mkf2(s0r[0] + s1i[0], s1r[0] - s0i[0]);
    }
    int f1 = f0 + 1;
    z[zp(f1)]        = mkf2(s0r[1] - s1i[1], s0i[1] + s1r[1]);
    z[zp(2048 - f1)] = mkf2(s0r[1] + s1i[1], s1r[1] - s0i[1]);
  }
  __syncthreads();
  fft2048<true>(z, tw, tid);
  f16* sdst = spec + (size_t)(model * 2048 + b * 1024) * 512;
  for (int t = tid; t < 1024; t += 256) {
    float2 v = z[zp(t)];
    union { f16 h[2]; unsigned u; } pk;
    pk.h[0] = (f16)v.x; pk.h[1] = (f16)v.y;
    *(unsigned*)(sdst + (size_t)t * 512 + o0) = pk.u;
  }
}

// ---------------- gemm0: spectral GEMM both models, BK=64 round-2 structure ----------------
__global__ __launch_bounds__(256, 2)
void k_gemm0(const f16* __restrict__ A0, const f16* __restrict__ B00,
             const float* __restrict__ aux0, f16* __restrict__ outP) {
  __shared__ __align__(16) f16 As[128 * 64];
  __shared__ __align__(16) f16 Bs[128 * 64];
  const int tid = threadIdx.x, l = tid & 63, wvi = tid >> 6;
  const int wr = wvi >> 1, wc = wvi & 1;
  int wg = (int)blockIdx.x;            // 1024 = 8 * 128, bijective XCD chunk swizzle
  wg = (wg & 7) * 128 + (wg >> 3);
  const int model = wg >> 9;
  int rem = wg & 511;
  const int bz = rem >> 7; rem &= 127;
  const int by = rem >> 2, bx = rem & 3;
  const int r0 = by * 128, c0 = bx * 128;
  const f16* A  = A0  + (size_t)model * RTOT * 512;
  const f16* B0 = B00 + (size_t)model * 16384 * 512;

  f32x4 acc[4][4];
  f32x4 crun[4][4];
  f32x4 zz = {0.f, 0.f, 0.f, 0.f};
#pragma unroll
  for (int m = 0; m < 4; ++m)
#pragma unroll
    for (int n = 0; n < 4; ++n) { acc[m][n] = zz; crun[m][n] = zz; }

  const int rowl = tid >> 3;
  const int lc8 = ((tid & 7) ^ (rowl & 7)) * 8;   // swizzled chunk * 8 (f16)
  f16* lA = As + ((tid >> 6) << 9);
  f16* lB = Bs + ((tid >> 6) << 9);
  const int lr = l & 15, kg = l >> 4, sw = l & 7;

  for (int s = 0; s < 64; ++s) {
    __syncthreads();                   // prior mma's LDS reads done
    {
      const int kA = (s & 7) * 64;
      const int kb = bz * 8 + (s >> 3);
#pragma unroll
      for (int i = 0; i < 4; ++i) {
        gl16(A + (size_t)(r0 + i * 32 + rowl) * 512 + kA + lc8, lA + i * 2048);
        gl16(B0 + (size_t)(kb * 512 + c0 + i * 32 + rowl) * 512 + kA + lc8, lB + i * 2048);
      }
    }
    __syncthreads();                   // staging landed (compiler drains vmcnt)
#pragma unroll
    for (int kk = 0; kk < 2; ++kk) {
      half8 af[4], bf[4];
      const int pc8 = (((kk * 4 + kg) ^ sw) << 3);
#pragma unroll
      for (int m = 0; m < 4; ++m)
        af[m] = *(const half8*)(As + (wr * 64 + m * 16 + lr) * 64 + pc8);
#pragma unroll
      for (int n = 0; n < 4; ++n)
        bf[n] = *(const half8*)(Bs + (wc * 64 + n * 16 + lr) * 64 + pc8);
#pragma unroll
      for (int m = 0; m < 4; ++m)
#pragma unroll
        for (int n = 0; n < 4; ++n)
          acc[m][n] = __builtin_amdgcn_mfma_f32_16x16x32_f16(af[m], bf[n], acc[m][n], 0, 0, 0);
    }
    if ((s & 7) == 7) {
      int kb = bz * 8 + (s >> 3);
#pragma unroll
      for (int m = 0; m < 4; ++m) {
        int R = r0 + wr * 64 + m * 16 + (kg << 2);
        int rb = R & (RPB - 1);
        bool dc = (rb == 0);           // rows 0,1 = packed (DC.re, Nyq.re): scale separately
        float4 cs = *(const float4*)(aux0 + (size_t)kb * (CPS * 2) + (rb >> 1) * 2);
        float t1 = dc ? 0.f : cs.y;
        float t2 = dc ? cs.y : cs.x;
#pragma unroll
        for (int n = 0; n < 4; ++n) {
          f32x4 p = acc[m][n];
          crun[m][n].x += cs.x * p.x - t1 * p.y;
          crun[m][n].y += t2 * p.y + t1 * p.x;
          crun[m][n].z += cs.z * p.z - cs.w * p.w;
          crun[m][n].w += cs.z * p.w + cs.w * p.z;
          acc[m][n] = zz;
        }
      }
    }
  }

  f16* P = outP + (size_t)bz * (2ull * 512 * RTOT) + (size_t)model * 512 * RTOT;
#pragma unroll
  for (int m = 0; m < 4; ++m) {
    int R0 = r0 + wr * 64 + m * 16 + (kg << 2);
#pragma unroll
    for (int n = 0; n < 4; ++n) {
      int o = c0 + wc * 64 + n * 16 + lr;
      union { f16 h[4]; uint2 u; } pk;
      pk.h[0] = (f16)crun[m][n].x; pk.h[1] = (f16)crun[m][n].y;
      pk.h[2] = (f16)crun[m][n].z; pk.h[3] = (f16)crun[m][n].w;
      *(uint2*)(P + (size_t)o * RTOT + R0) = pk.u;
    }
  }
}

// ---------------- generic MFMA GEMM (modes 1-3, BK=64, both models via by) ----------
template<int MODE, int MR, int NR>
__device__ __forceinline__ void stage(const f16* __restrict__ A, const f16* __restrict__ B0,
                                      int r0, int c0, int tid, int s,
                                      f16* As, f16* Bs) {
  constexpr int LDA = (MODE == 1) ? 1536 : (MODE == 2) ? 512 : 2048;
  const int kA = s * 64;
  const int rowl = tid >> 3;
  const int lc8 = ((tid & 7) ^ (rowl & 7)) * 8;   // swizzled chunk * 8 (f16)
  f16* lA = As + ((tid >> 6) << 9);
  f16* lB = Bs + ((tid >> 6) << 9);
#pragma unroll
  for (int i = 0; i < MR; ++i) {
    int row = i * 32 + rowl;
    gl16(A + (size_t)(r0 + row) * LDA + kA + lc8, lA + i * 2048);
  }
#pragma unroll
  for (int i = 0; i < NR; ++i) {
    int row = i * 32 + rowl;
    const f16* bs;
    if constexpr (MODE == 1) {
      int ip = s >> 3, d0 = (s & 7) * 64;
      int rr = c0 + row;
      int b = rr >> 10, t = rr & 1023;
      bs = B0 + (size_t)(b * 1026 + t + ip) * 512 + d0 + lc8;   // pad rows are zero
    } else {
      constexpr int LDB = (MODE == 2) ? 512 : 2048;
      bs = B0 + (size_t)(c0 + row) * LDB + s * 64 + lc8;
    }
    gl16(bs, lB + i * 2048);
  }
}

template<int MR, int NR>
__device__ __forceinline__ void mma_step(const f16* As, const f16* Bs, int l, int wr, int wc,
                                         f32x4 acc[MR][NR]) {
  const int lr = l & 15, kg = l >> 4, sw = l & 7;
#pragma unroll
  for (int kk = 0; kk < 2; ++kk) {
    half8 af[MR], bf[NR];
    const int pc8 = (((kk * 4 + kg) ^ sw) << 3);
#pragma unroll
    for (int m = 0; m < MR; ++m)
      af[m] = *(const half8*)(As + (wr * (MR * 16) + m * 16 + lr) * 64 + pc8);
#pragma unroll
    for (int n = 0; n < NR; ++n)
      bf[n] = *(const half8*)(Bs + (wc * (NR * 16) + n * 16 + lr) * 64 + pc8);
#pragma unroll
    for (int m = 0; m < MR; ++m)
#pragma unroll
      for (int n = 0; n < NR; ++n)
        acc[m][n] = __builtin_amdgcn_mfma_f32_16x16x32_f16(af[m], bf[n], acc[m][n], 0, 0, 0);
  }
}

template<int MODE, int MR, int NR>
__global__ __launch_bounds__(256, (MODE == 2) ? 3 : 4)
void k_gemm(const f16* __restrict__ Ain, const f16* __restrict__ Bin,
            const f16* auxAin, const f16* auxBin, f16* __restrict__ outIn) {
  __shared__ __align__(16) f16 As[MR * 32 * 64];
  __shared__ __align__(16) f16 Bs[NR * 32 * 64];
  const int tid = threadIdx.x, l = tid & 63, wvi = tid >> 6;
  const int wr = wvi >> 1, wc = wvi & 1;
  const int bx = blockIdx.x, byi = blockIdx.y;
  constexpr int BYD = (MODE == 2) ? 32 : 8;      // y-blocks per model
  const int model = byi / BYD, by = byi % BYD;
  const int r0 = by * (MR * 32), c0 = bx * (NR * 32);
  constexpr int KS = (MODE == 1) ? 24 : (MODE == 2) ? 8 : 32;
  const size_t actOff = (size_t)model * 2048 * 512;
  const f16* A = Ain + (size_t)model *
      ((MODE == 1) ? 512ull * 1536 : (MODE == 2) ? 4096ull * 512 : 512ull * 2048);
  const f16* B0 = Bin + ((MODE == 1) ? (size_t)model * 2 * 1026 * 512 :
                         (MODE == 2) ? actOff : (size_t)model * 2048 * 2048);
  const f16* auxA = auxAin + actOff;
  const f16* auxB = auxBin + actOff;
  f16* outH = outIn + ((MODE == 2) ? (size_t)model * 2048 * 2048 : actOff);

  f32x4 acc[MR][NR];
  f32x4 zz = {0.f, 0.f, 0.f, 0.f};
#pragma unroll
  for (int m = 0; m < MR; ++m)
#pragma unroll
    for (int n = 0; n < NR; ++n) acc[m][n] = zz;

  for (int s = 0; s < KS; ++s) {
    __syncthreads();
    stage<MODE, MR, NR>(A, B0, r0, c0, tid, s, As, Bs);
    __syncthreads();
    mma_step<MR, NR>(As, Bs, l, wr, wc, acc);
  }

  if constexpr (MODE == 1) {
#pragma unroll
    for (int m = 0; m < MR; ++m) {
      int o0 = r0 + wr * (MR * 16) + m * 16 + ((l >> 4) << 2);
#pragma unroll
      for (int n = 0; n < NR; ++n) {
        int r = c0 + wc * (NR * 16) + n * 16 + (l & 15);
        union { uint2 u; f16 h[4]; } xv, sv;
        xv.u = *(const uint2*)(auxA + (size_t)r * 512 + o0);
        sv.u = *(const uint2*)(auxB + (size_t)r * 512 + o0);
        f32x4 a = acc[m][n];
        union { f16 h[4]; uint2 u; } pk;
        pk.h[0] = (f16)((float)xv.h[0] + (float)sv.h[0] + a.x);
        pk.h[1] = (f16)((float)xv.h[1] + (float)sv.h[1] + a.y);
        pk.h[2] = (f16)((float)xv.h[2] + (float)sv.h[2] + a.z);
        pk.h[3] = (f16)((float)xv.h[3] + (float)sv.h[3] + a.w);
        *(uint2*)(outH + (size_t)r * 512 + o0) = pk.u;
      }
    }
  } else if constexpr (MODE == 2) {
#pragma unroll
    for (int m = 0; m < MR; ++m) {
      int jj0 = r0 + wr * (MR * 16) + m * 16 + ((l >> 4) << 2);
      int h2 = jj0 >> 1;
#pragma unroll
      for (int n = 0; n < NR; ++n) {
        int r = c0 + wc * (NR * 16) + n * 16 + (l & 15);
        f32x4 a = acc[m][n];
        float v0 = a.x * (a.y / (1.f + __expf(-a.y)));
        float v1 = a.z * (a.w / (1.f + __expf(-a.w)));
        union { f16 h[2]; unsigned u; } pk;
        pk.h[0] = (f16)v0; pk.h[1] = (f16)v1;
        *(unsigned*)(outH + (size_t)r * 2048 + h2) = pk.u;
      }
    }
  } else {
#pragma unroll
    for (int m = 0; m < MR; ++m) {
      int o0 = r0 + wr * (MR * 16) + m * 16 + ((l >> 4) << 2);
#pragma unroll
      for (int n = 0; n < NR; ++n) {
        int r = c0 + wc * (NR * 16) + n * 16 + (l & 15);
        union { uint2 u; f16 h[4]; } xv, x1v;
        xv.u  = *(const uint2*)(auxA + (size_t)r * 512 + o0);
        x1v.u = *(const uint2*)(auxB + (size_t)r * 512 + o0);
        f32x4 a = acc[m][n];
        union { f16 h[4]; uint2 u; } pk;
        pk.h[0] = (f16)((float)xv.h[0] + (float)x1v.h[0] + a.x);
        pk.h[1] = (f16)((float)xv.h[1] + (float)x1v.h[1] + a.y);
        pk.h[2] = (f16)((float)xv.h[2] + (float)x1v.h[2] + a.z);
        pk.h[3] = (f16)((float)xv.h[3] + (float)x1v.h[3] + a.w);
        *(uint2*)(outH + (size_t)r * 512 + o0) = pk.u;
      }
    }
  }
}

// ---------------- small projections ----------------
__global__ void k_inproj(const float* __restrict__ inp, const float* __restrict__ Wall,
                         f16* __restrict__ x) {
  __shared__ float row[64];
  int r = blockIdx.x, tid = threadIdx.x;     // r in 0..4095
  int model = r >> 11, rl = r & 2047;
  const float* W = Wall + (size_t)model * 512 * 64;
  if (tid < 64) row[tid] = inp[(size_t)rl * 64 + tid];
  __syncthreads();
  for (int o = tid; o < 512; o += 256) {
    const float* wr = W + (size_t)o * 64;
    float acc = 0.f;
#pragma unroll 8
    for (int q = 0; q < 64; ++q) acc += row[q] * wr[q];
    x[(size_t)r * 512 + o] = (f16)acc;
  }
}

// out[r] = x_m0[r] @ W0^T + x_m1[r] @ W1^T  (single kernel, both models)
__global__ void k_outproj(const f16* __restrict__ x, const float* __restrict__ Wall,
                          float* out) {
  __shared__ float row[1024];
  int r = blockIdx.x, tid = threadIdx.x;
  for (int i = tid; i < 1024; i += 256) {
    int mdl = i >> 9, c = i & 511;
    row[i] = (float)x[((size_t)mdl * 2048 + r) * 512 + c];
  }
  __syncthreads();
  int o = tid >> 2, part = tid & 3;
  const float* w0 = Wall + (size_t)o * 512 + part * 128;
  const float* w1 = Wall + 64ull * 512 + (size_t)o * 512 + part * 128;
  const float* r0 = row + part * 128;
  const float* r1 = row + 512 + part * 128;
  float acc = 0.f;
#pragma unroll 16
  for (int q = 0; q < 128; ++q) acc += r0[q] * w0[q] + r1[q] * w1[q];
  acc += __shfl_xor(acc, 1, 64);
  acc += __shfl_xor(acc, 2, 64);
  if (part == 0) out[(size_t)r * 64 + o] = acc;
}

// ---------------- host ----------------
extern "C" void kernel_launch(void* const* d_in, const int* in_sizes, int n_in,
                              void* d_out, int out_size, void* d_ws, size_t ws_size,
                              hipStream_t stream) {
  const float* inputs    = (const float*)d_in[0];
  const float* sigma     = (const float*)d_in[1];
  const float* phi       = (const float*)d_in[2];
  const float* in_proj_w = (const float*)d_in[3];
  const float* rn_w      = (const float*)d_in[4];
  const float* M_u       = (const float*)d_in[5];
  const float* M_phi_p   = (const float*)d_in[6];
  const float* M_phi_m   = (const float*)d_in[7];
  const float* fc1       = (const float*)d_in[8];
  const float* fc2       = (const float*)d_in[9];
  const float* out_proj_w= (const float*)d_in[10];
  float* out = (float*)d_out;

  char* ws = (char*)d_ws;
  size_t off = 0;
  auto alloc = [&](size_t bytes) -> void* {
    void* p = ws + off;
    off += (bytes + 255) & ~(size_t)255;
    return p;
  };
  float2* tw   = (float2*)alloc(1024 * 8);
  float2* Vf   = (float2*)alloc((size_t)16 * 1025 * 8);
  float2* cpcm = (float2*)alloc((size_t)32 * CPS * 8);
  f16*    x    = (f16*)alloc((size_t)2 * NROW * 512 * 2);
  f16*    hb2  = (f16*)alloc((size_t)4 * 1026 * 512 * 2);   // 2 models x 2 batches
  f16*    x1   = (f16*)alloc((size_t)2 * NROW * 512 * 2);
  f16*    spec = (f16*)alloc((size_t)2 * NROW * 512 * 2);
  f16*    Xbf  = (f16*)alloc((size_t)2 * RTOT * 512 * 2);
  f16*    P    = (f16*)alloc((size_t)NPART * 2 * 512 * RTOT * 2);
  f16*    g1   = (f16*)alloc((size_t)2 * NROW * 2048 * 2);
  f16*    Wsp  = (f16*)alloc((size_t)2 * 16384 * 512 * 2);
  f16*    Wu   = (f16*)alloc((size_t)2 * 512 * 1536 * 2);
  f16*    Wf1  = (f16*)alloc((size_t)2 * 4096 * 512 * 2);
  f16*    Wf2  = (f16*)alloc((size_t)2 * 512 * 2048 * 2);
  if (off > ws_size) return;  // workspace too small: fail loudly (output stays poisoned)

  // zero the AR window pad rows (rows 0,1 of each of the 4 batch blocks)
  for (int k = 0; k < 4; ++k)
    hipMemsetAsync(hb2 + (size_t)k * 1026 * 512, 0, 2 * 512 * sizeof(f16), stream);
  k_twiddle<<<4, 256, 0, stream>>>(tw);
  k_fft_phi<<<8, 256, 0, stream>>>(phi, Vf, tw);
  k_cpcm<<<133, 256, 0, stream>>>(Vf, sigma, cpcm);

  k_inproj<<<4096, 256, 0, stream>>>(inputs, in_proj_w, x);
  for (int li = 0; li < 2; ++li) {
    k_rmsnorm<<<1024, 256, 0, stream>>>(x, rn_w, li, hb2);
    k_fwdcast<<<1024 + 7552, 256, 0, stream>>>(
        hb2, Xbf, tw, li, M_phi_p, M_phi_m, M_u, fc1, fc2, Wsp, Wu, Wf1, Wf2);
    k_gemm0<<<dim3(1024), 256, 0, stream>>>(Xbf, Wsp, (const float*)cpcm, P);
    k_fft_inv<<<1024, 256, 0, stream>>>(P, spec, tw);
    k_gemm<1, 2, 2><<<dim3(32, 16), 256, 0, stream>>>(Wu, hb2, x, spec, x1);
    k_gemm<2, 4, 4><<<dim3(16, 64), 256, 0, stream>>>(Wf1, x1, nullptr, nullptr, g1);
    k_gemm<3, 2, 2><<<dim3(32, 16), 256, 0, stream>>>(Wf2, g1, x, x1, x);
  }
  k_outproj<<<NROW, 256, 0, stream>>>(x, out_proj_w, out);
}

// Round 15
// 749.101 us; speedup vs baseline: 1.1058x; 1.0435x over previous
//
#include <hip/hip_runtime.h>
#include <hip/hip_bf16.h>

typedef _Float16 f16;
typedef _Float16 half8 __attribute__((ext_vector_type(8)));
typedef float f32x4 __attribute__((ext_vector_type(4)));

#define S_LEN 1024
#define DMODEL 512
#define NFFT   2048
#define RPB    2048     // rows per batch: f=1..1023 pairs + packed (DC.re, Nyq.re) in rows 0,1
#define RTOT   4096     // per-model: 2 batches -> exactly 32 row-tiles of 128
#define CPS    1064     // cpcm f-stride
#define NROW   2048     // B*S per model
#define NPART  2        // split-K partials (gemm0 grid 512 = exactly 1 generation)

__device__ __forceinline__ float2 mkf2(float a, float b) { float2 r; r.x = a; r.y = b; return r; }
__device__ __forceinline__ int zp(int i) { return i + (i >> 5); }   // LDS bank-pad for FFT array
__device__ __forceinline__ float2 cmul(float2 w, float2 b) {
  return mkf2(b.x * w.x - b.y * w.y, b.x * w.y + b.y * w.x);
}
__device__ __forceinline__ float2 f2a(float2 a, float2 b) { return mkf2(a.x + b.x, a.y + b.y); }
__device__ __forceinline__ float2 f2s(float2 a, float2 b) { return mkf2(a.x - b.x, a.y - b.y); }

// async global->LDS (16B per lane). LDS dest must be wave-uniform base; lane writes at +lane*16.
__device__ __forceinline__ void gl16(const f16* g, f16* l) {
  __builtin_amdgcn_global_load_lds((const __attribute__((address_space(1))) void*)g,
                                   (__attribute__((address_space(3))) void*)l, 16, 0, 0);
}

// ---------------- FFT-2048 in LDS: 3x radix-8 + 1x radix-4, padded indexing ----------------
template<bool INV>
__device__ __forceinline__ void fft2048(float2* z, const float2* __restrict__ tw, int tid) {
  for (int i = tid; i < 2048; i += 256) {
    int j = (int)(__brev((unsigned)i) >> 21);
    if (i < j) { float2 a = z[zp(i)]; z[zp(i)] = z[zp(j)]; z[zp(j)] = a; }
  }
  __syncthreads();
#pragma unroll
  for (int r8 = 0; r8 < 3; ++r8) {       // fused stages (1,2,3),(4,5,6),(7,8,9)
    const int sl = 1 + 3 * r8;
    const int h = 1 << (sl - 1);
    {
      int q = tid;                        // 256 groups of 8, one per thread
      int j = q & (h - 1);
      int i0 = ((q >> (sl - 1)) << (sl + 2)) + j;
      float2 a0 = z[zp(i0)],         a1 = z[zp(i0 + h)];
      float2 a2 = z[zp(i0 + 2 * h)], a3 = z[zp(i0 + 3 * h)];
      float2 a4 = z[zp(i0 + 4 * h)], a5 = z[zp(i0 + 5 * h)];
      float2 a6 = z[zp(i0 + 6 * h)], a7 = z[zp(i0 + 7 * h)];
      float2 wA  = tw[j << (11 - sl)];
      float2 wB0 = tw[j << (10 - sl)];
      float2 wB1 = tw[(j + h) << (10 - sl)];
      float2 wC0 = tw[j << (9 - sl)];
      float2 wC1 = tw[(j + h) << (9 - sl)];
      float2 wC2 = tw[(j + 2 * h) << (9 - sl)];
      float2 wC3 = tw[(j + 3 * h) << (9 - sl)];
      if (INV) {
        wA.y = -wA.y; wB0.y = -wB0.y; wB1.y = -wB1.y;
        wC0.y = -wC0.y; wC1.y = -wC1.y; wC2.y = -wC2.y; wC3.y = -wC3.y;
      }
      float2 t;
      t = cmul(wA, a1); float2 b0 = f2a(a0, t), b1 = f2s(a0, t);
      t = cmul(wA, a3); float2 b2 = f2a(a2, t), b3 = f2s(a2, t);
      t = cmul(wA, a5); float2 b4 = f2a(a4, t), b5 = f2s(a4, t);
      t = cmul(wA, a7); float2 b6 = f2a(a6, t), b7 = f2s(a6, t);
      t = cmul(wB0, b2); float2 c0 = f2a(b0, t), c2 = f2s(b0, t);
      t = cmul(wB1, b3); float2 c1 = f2a(b1, t), c3 = f2s(b1, t);
      t = cmul(wB0, b6); float2 c4 = f2a(b4, t), c6 = f2s(b4, t);
      t = cmul(wB1, b7); float2 c5 = f2a(b5, t), c7 = f2s(b5, t);
      t = cmul(wC0, c4); z[zp(i0)]         = f2a(c0, t); z[zp(i0 + 4 * h)] = f2s(c0, t);
      t = cmul(wC1, c5); z[zp(i0 + h)]     = f2a(c1, t); z[zp(i0 + 5 * h)] = f2s(c1, t);
      t = cmul(wC2, c6); z[zp(i0 + 2 * h)] = f2a(c2, t); z[zp(i0 + 6 * h)] = f2s(c2, t);
      t = cmul(wC3, c7); z[zp(i0 + 3 * h)] = f2a(c3, t); z[zp(i0 + 7 * h)] = f2s(c3, t);
    }
    __syncthreads();
  }
  for (int q = tid; q < 512; q += 256) {  // final radix-4 round: stages (10,11)
    float2 a0 = z[zp(q)], a1 = z[zp(q + 512)], a2 = z[zp(q + 1024)], a3 = z[zp(q + 1536)];
    float2 w1 = tw[q << 1], w2 = tw[q], w3 = tw[q + 512];
    if (INV) { w1.y = -w1.y; w2.y = -w2.y; w3.y = -w3.y; }
    float2 t;
    t = cmul(w1, a1); float2 b0 = f2a(a0, t), b1 = f2s(a0, t);
    t = cmul(w1, a3); float2 b2 = f2a(a2, t), b3 = f2s(a2, t);
    t = cmul(w2, b2); z[zp(q)]        = f2a(b0, t); z[zp(q + 1024)] = f2s(b0, t);
    t = cmul(w3, b3); z[zp(q + 512)]  = f2a(b1, t); z[zp(q + 1536)] = f2s(b1, t);
  }
  __syncthreads();
}

// ---------------- init kernels ----------------
__global__ void k_twiddle(float2* tw) {
  int i = blockIdx.x * 256 + threadIdx.x;
  if (i < 1024) {
    float ang = -6.2831853071795864769f * (float)i / 2048.0f;
    tw[i] = mkf2(cosf(ang), sinf(ang));
  }
}

// rfft of phi columns (pairs packed into one complex FFT)
__global__ void k_fft_phi(const float* __restrict__ phi, float2* __restrict__ Vf,
                          const float2* __restrict__ tw) {
  __shared__ float2 z[2112];
  int tid = threadIdx.x;
  int k0 = blockIdx.x * 2;
  for (int t = tid; t < 1024; t += 256)
    z[zp(t)] = *(const float2*)(phi + (size_t)t * 16 + k0);
  for (int t = 1024 + tid; t < 2048; t += 256) z[zp(t)] = mkf2(0.f, 0.f);
  __syncthreads();
  fft2048<false>(z, tw, tid);
  for (int f = tid; f <= 1024; f += 256) {
    float2 zf = z[zp(f)], zc = z[zp((2048 - f) & 2047)];
    Vf[(size_t)k0 * 1025 + f]       = mkf2(0.5f * (zf.x + zc.x), 0.5f * (zf.y - zc.y));
    Vf[(size_t)(k0 + 1) * 1025 + f] = mkf2(0.5f * (zf.y + zc.y), 0.5f * (zc.x - zf.x));
  }
}

// cpcm[kb][f]: f=1..1023 standard complex scale; slot 0 packs (c_DC, c_Nyq) (both REAL).
__global__ void k_cpcm(const float2* __restrict__ Vf, const float* __restrict__ sigma,
                       float2* __restrict__ cpcm) {
  int idx = blockIdx.x * 256 + threadIdx.x;
  if (idx >= 32 * CPS) return;
  int kb = idx / CPS, f = idx - kb * CPS;
  int k = kb & 15;
  float s = powf(sigma[k], 0.25f) * (1.0f / 2048.0f);
  float2 v = mkf2(0.f, 0.f);
  if (f == 0) {
    float dc = Vf[(size_t)k * 1025].x;          // real
    float ny = Vf[(size_t)k * 1025 + 1024].x;   // real
    v = (kb < 16) ? mkf2(s * dc, s * ny) : mkf2(s * ny, s * dc);
  } else if (f <= 1023) {
    if (kb < 16) {
      v = Vf[(size_t)k * 1025 + f];
    } else {
      float2 t = Vf[(size_t)k * 1025 + (1024 - f)];
      v = mkf2(t.x, -t.y);
    }
    v.x *= s; v.y *= s;
  }
  cpcm[idx] = v;
}

// ---------------- generic GEMM helpers (BK=64) ----------------
template<int MODE, int MR, int NR>
__device__ __forceinline__ void stage(const f16* __restrict__ A, const f16* __restrict__ B0,
                                      int r0, int c0, int tid, int s,
                                      f16* As, f16* Bs) {
  constexpr int LDA = (MODE == 1) ? 1536 : (MODE == 2) ? 512 : 2048;
  const int kA = s * 64;
  const int rowl = tid >> 3;
  const int lc8 = ((tid & 7) ^ (rowl & 7)) * 8;   // swizzled chunk * 8 (f16)
  f16* lA = As + ((tid >> 6) << 9);
  f16* lB = Bs + ((tid >> 6) << 9);
#pragma unroll
  for (int i = 0; i < MR; ++i) {
    int row = i * 32 + rowl;
    gl16(A + (size_t)(r0 + row) * LDA + kA + lc8, lA + i * 2048);
  }
#pragma unroll
  for (int i = 0; i < NR; ++i) {
    int row = i * 32 + rowl;
    const f16* bs;
    if constexpr (MODE == 1) {
      int ip = s >> 3, d0 = (s & 7) * 64;
      int rr = c0 + row;
      int b = rr >> 10, t = rr & 1023;
      bs = B0 + (size_t)(b * 1026 + t + ip) * 512 + d0 + lc8;   // pad rows are zero
    } else {
      constexpr int LDB = (MODE == 2) ? 512 : 2048;
      bs = B0 + (size_t)(c0 + row) * LDB + s * 64 + lc8;
    }
    gl16(bs, lB + i * 2048);
  }
}

template<int MR, int NR>
__device__ __forceinline__ void mma_step(const f16* As, const f16* Bs, int l, int wr, int wc,
                                         f32x4 acc[MR][NR]) {
  const int lr = l & 15, kg = l >> 4, sw = l & 7;
#pragma unroll
  for (int kk = 0; kk < 2; ++kk) {
    half8 af[MR], bf[NR];
    const int pc8 = (((kk * 4 + kg) ^ sw) << 3);
#pragma unroll
    for (int m = 0; m < MR; ++m)
      af[m] = *(const half8*)(As + (wr * (MR * 16) + m * 16 + lr) * 64 + pc8);
#pragma unroll
    for (int n = 0; n < NR; ++n)
      bf[n] = *(const half8*)(Bs + (wc * (NR * 16) + n * 16 + lr) * 64 + pc8);
#pragma unroll
    for (int m = 0; m < MR; ++m)
#pragma unroll
      for (int n = 0; n < NR; ++n)
        acc[m][n] = __builtin_amdgcn_mfma_f32_16x16x32_f16(af[m], bf[n], acc[m][n], 0, 0, 0);
  }
}

// ---------------- merged per-layer: fwd FFT (0..1023) + AR gemm1 (1024..1535) + cast ----------
// All three depend only on prior-launch outputs (hb2, x, pre-cast Wu) -> safe same-launch merge.
// gemm1 writes x1p = x + AR(h); spec is added later inside fft_inv.
__global__ __launch_bounds__(256)
void k_fwdcast(const f16* __restrict__ hb2, f16* __restrict__ Xbf,
               const float2* __restrict__ tw, int li,
               const float* __restrict__ Mp, const float* __restrict__ Mm,
               const float* __restrict__ Fc1, const float* __restrict__ Fc2,
               f16* __restrict__ Wsp, const f16* __restrict__ WuAll,
               f16* __restrict__ Wf1, f16* __restrict__ Wf2,
               const f16* __restrict__ x, f16* __restrict__ x1p) {
  __shared__ __align__(16) char smem[16896];
  int wg = (int)blockIdx.x, tid = threadIdx.x;
  if (wg < 1024) {
    // ---- forward FFT of hb2 -> Xbf; rows 0,1 = (DC.re, Nyq.re), rows 2f,2f+1 f=1..1023
    float2* z = (float2*)smem;
    int model = wg >> 9;
    int b = (wg >> 8) & 1;
    int d0 = (wg & 255) * 2;
    const f16* hsrc = hb2 + (size_t)(model * 2 + b) * 1026 * 512;
    f16* xdst = Xbf + (size_t)model * RTOT * 512 + (size_t)b * RPB * 512;
    for (int t = tid; t < 1024; t += 256) {
      union { unsigned v; f16 q[2]; } w;
      w.v = *(const unsigned*)(hsrc + (size_t)(2 + t) * 512 + d0);
      z[zp(t)] = mkf2((float)w.q[0], (float)w.q[1]);
    }
    for (int t = 1024 + tid; t < 2048; t += 256) z[zp(t)] = mkf2(0.f, 0.f);
    __syncthreads();
    fft2048<false>(z, tw, tid);
    for (int f = tid; f <= 1024; f += 256) {
      float2 zf = z[zp(f)], zc = z[zp((2048 - f) & 2047)];
      float x0r = 0.5f * (zf.x + zc.x), x0i = 0.5f * (zf.y - zc.y);
      float x1r = 0.5f * (zf.y + zc.y), x1i = 0.5f * (zc.x - zf.x);
      union { f16 h2[2]; unsigned u; } pr, pi;
      pr.h2[0] = (f16)x0r; pr.h2[1] = (f16)x1r;
      pi.h2[0] = (f16)x0i; pi.h2[1] = (f16)x1i;
      if (f == 0) {
        *(unsigned*)(xdst + d0) = pr.u;                                  // DC (im=0)
      } else if (f == 1024) {
        *(unsigned*)(xdst + (size_t)512 + d0) = pr.u;                    // Nyquist (im=0)
      } else {
        *(unsigned*)(xdst + (size_t)(2 * f) * 512 + d0)     = pr.u;
        *(unsigned*)(xdst + (size_t)(2 * f + 1) * 512 + d0) = pi.u;
      }
    }
    return;
  }
  if (wg < 1536) {
    // ---- AR gemm1 (MODE 1): x1p = x + AR(h), 64x64 tiles, KS=24
    f16* As = (f16*)smem;
    f16* Bs = (f16*)smem + 4096;
    int q = wg - 1024;
    const int bx = q & 31, byi = q >> 5;
    const int model = byi >> 3, by = byi & 7;
    const int r0 = by * 64, c0 = bx * 64;
    const int l = tid & 63, wvi = tid >> 6;
    const int wr = wvi >> 1, wc = wvi & 1;
    const f16* A  = WuAll + ((size_t)li * 2 + model) * (512ull * 1536);
    const f16* B0 = hb2 + (size_t)model * 2 * 1026 * 512;
    const f16* xM  = x  + (size_t)model * 2048 * 512;
    f16* x1pM      = x1p + (size_t)model * 2048 * 512;

    f32x4 acc[2][2];
    f32x4 zz = {0.f, 0.f, 0.f, 0.f};
#pragma unroll
    for (int m = 0; m < 2; ++m)
#pragma unroll
      for (int n = 0; n < 2; ++n) acc[m][n] = zz;

    for (int s = 0; s < 24; ++s) {
      __syncthreads();
      stage<1, 2, 2>(A, B0, r0, c0, tid, s, As, Bs);
      __syncthreads();
      mma_step<2, 2>(As, Bs, l, wr, wc, acc);
    }
#pragma unroll
    for (int m = 0; m < 2; ++m) {
      int o0 = r0 + wr * 32 + m * 16 + ((l >> 4) << 2);
#pragma unroll
      for (int n = 0; n < 2; ++n) {
        int r = c0 + wc * 32 + n * 16 + (l & 15);
        union { uint2 u; f16 h[4]; } xv;
        xv.u = *(const uint2*)(xM + (size_t)r * 512 + o0);
        f32x4 a = acc[m][n];
        union { f16 h[4]; uint2 u; } pk;
        pk.h[0] = (f16)((float)xv.h[0] + a.x);
        pk.h[1] = (f16)((float)xv.h[1] + a.y);
        pk.h[2] = (f16)((float)xv.h[2] + a.z);
        pk.h[3] = (f16)((float)xv.h[3] + a.w);
        *(uint2*)(x1pM + (size_t)r * 512 + o0) = pk.u;
      }
    }
    return;
  }
  // ---- weight cast/transpose for BOTH models (Wsp, fc1, fc2), T[64][65] in smem
  float* T = (float*)smem;
  int q0all = wg - 1536;               // 0..7167
  int model = q0all & 1;
  int blk = q0all >> 1;                // 0..3583
  int ml = model * 2 + li;
  const float* mp  = Mp  + (size_t)ml * 16 * 262144;
  const float* mm  = Mm  + (size_t)ml * 16 * 262144;
  const float* fc1 = Fc1 + (size_t)ml * 4096 * 512;
  const float* fc2 = Fc2 + (size_t)ml * 512 * 2048;
  f16* WspM = Wsp + (size_t)model * 16384 * 512;
  f16* Wf1M = Wf1 + (size_t)model * 4096 * 512;
  f16* Wf2M = Wf2 + (size_t)model * 512 * 2048;
  if (blk < 2048) {                    // Wsp: Wsp[(kb*512+o)][d] = m?[k][d][o]
    int mat = blk >> 6, tile = blk & 63;
    int d0 = (tile >> 3) * 64, o0 = (tile & 7) * 64;
    const float* src = (mat < 16) ? (mp + (size_t)mat * 262144)
                                  : (mm + (size_t)(mat - 16) * 262144);
    for (int q = tid; q < 4096; q += 256) {
      int i = q >> 6, j = q & 63;
      T[i * 65 + j] = src[(size_t)(d0 + i) * 512 + o0 + j];
    }
    __syncthreads();
    for (int q = tid; q < 4096; q += 256) {
      int i = q >> 6, j = q & 63;
      WspM[(size_t)(mat * 512 + o0 + i) * 512 + d0 + j] = (f16)T[j * 65 + i];
    }
  } else if (blk < 3072) {             // fc1 perm copy: row 2h = y-row h, 2h+1 = gate-row h
    int q1 = blk - 2048;
    size_t e = ((size_t)q1 * 256 + tid) * 8;
    int jj = (int)(e >> 9), col = (int)(e & 511);
    int srow = (jj & 1) ? (2048 + (jj >> 1)) : (jj >> 1);
    const float4* s = (const float4*)(fc1 + (size_t)srow * 512 + col);
    float4 a = s[0], b = s[1];
    union { f16 h[8]; uint4 u; } pk;
    pk.h[0] = (f16)a.x; pk.h[1] = (f16)a.y; pk.h[2] = (f16)a.z; pk.h[3] = (f16)a.w;
    pk.h[4] = (f16)b.x; pk.h[5] = (f16)b.y; pk.h[6] = (f16)b.z; pk.h[7] = (f16)b.w;
    *(uint4*)(Wf1M + (size_t)jj * 512 + col) = pk.u;
  } else {                             // fc2 straight copy (already [o][j])
    int q1 = blk - 3072;
    size_t e = ((size_t)q1 * 256 + tid) * 8;
    const float4* s = (const float4*)(fc2 + e);
    float4 a = s[0], b = s[1];
    union { f16 h[8]; uint4 u; } pk;
    pk.h[0] = (f16)a.x; pk.h[1] = (f16)a.y; pk.h[2] = (f16)a.z; pk.h[3] = (f16)a.w;
    pk.h[4] = (f16)b.x; pk.h[5] = (f16)b.y; pk.h[6] = (f16)b.z; pk.h[7] = (f16)b.w;
    *(uint4*)(Wf2M + e) = pk.u;
  }
}

// ---------------- rmsnorm both models (grid 1024) ----------------
__global__ void k_rmsnorm(const f16* __restrict__ x, const float* __restrict__ rn_w, int li,
                          f16* __restrict__ hb2) {
  int tid = threadIdx.x, l = tid & 63, wv = tid >> 6;
  int r = blockIdx.x * 4 + wv;           // 0..4095 global row
  int model = r >> 11;
  int rl = r & 2047;
  int b = rl >> 10, t = rl & 1023;
  const float* w = rn_w + (size_t)(model * 2 + li) * 512;
  const f16* xr = x + (size_t)r * 512;
  f16* hr = hb2 + (size_t)((model * 2 + b) * 1026 + 2 + t) * 512;
  float v[8]; float ss = 0.f;
#pragma unroll
  for (int j = 0; j < 8; ++j) { v[j] = (float)xr[j * 64 + l]; ss += v[j] * v[j]; }
#pragma unroll
  for (int o = 32; o; o >>= 1) ss += __shfl_xor(ss, o, 64);
  float rn = rsqrtf(ss * (1.f / 512.f) + 1e-5f);
#pragma unroll
  for (int j = 0; j < 8; ++j) {
    float hv = v[j] * rn * w[j * 64 + l];
    hr[j * 64 + l] = (f16)hv;
  }
}

// ---------------- inverse FFT both models: sum NPART partials, fuse x1 = x1p + spec ----------
__global__ void k_fft_inv(const f16* __restrict__ P, const f16* __restrict__ x1p,
                          f16* __restrict__ x1, const float2* __restrict__ tw) {
  __shared__ float2 z[2112];
  int tid = threadIdx.x;
  int wg = (int)blockIdx.x;
  int model = wg >> 9;
  int b = (wg >> 8) & 1;
  int o0 = (wg & 255) * 2;
  const f16* Pm = P + (size_t)model * 512 * RTOT;
  for (int fp = tid; fp < 512; fp += 256) {
    int f0 = fp * 2;
    size_t base0 = (size_t)o0 * RTOT + (size_t)b * RPB + 2 * f0;
    float s0r[2] = {0.f, 0.f}, s0i[2] = {0.f, 0.f};
    float s1r[2] = {0.f, 0.f}, s1i[2] = {0.f, 0.f};
#pragma unroll
    for (int g = 0; g < NPART; ++g) {
      const f16* Pg = Pm + (size_t)g * (2ull * 512 * RTOT);
      union { uint2 u; f16 h[4]; } ua, uc;
      ua.u = *(const uint2*)(Pg + base0);
      uc.u = *(const uint2*)(Pg + base0 + RTOT);
      s0r[0] += (float)ua.h[0]; s0i[0] += (float)ua.h[1];
      s0r[1] += (float)ua.h[2]; s0i[1] += (float)ua.h[3];
      s1r[0] += (float)uc.h[0]; s1i[0] += (float)uc.h[1];
      s1r[1] += (float)uc.h[2]; s1i[1] += (float)uc.h[3];
    }
    if (fp == 0) {
      z[zp(0)]    = mkf2(s0r[0], s1r[0]);   // DC of both real o-channels
      z[zp(1024)] = mkf2(s0i[0], s1i[0]);   // Nyquist of both
    } else {
      z[zp(f0)]        = mkf2(s0r[0] - s1i[0], s0i[0] + s1r[0]);
      z[zp(2048 - f0)] = mkf2(s0r[0] + s1i[0], s1r[0] - s0i[0]);
    }
    int f1 = f0 + 1;
    z[zp(f1)]        = mkf2(s0r[1] - s1i[1], s0i[1] + s1r[1]);
    z[zp(2048 - f1)] = mkf2(s0r[1] + s1i[1], s1r[1] - s0i[1]);
  }
  __syncthreads();
  fft2048<true>(z, tw, tid);
  size_t rowOff = (size_t)(model * 2048 + b * 1024) * 512;
  const f16* psrc = x1p + rowOff;
  f16* pdst = x1 + rowOff;
  for (int t = tid; t < 1024; t += 256) {
    float2 v = z[zp(t)];
    union { unsigned u; f16 h[2]; } pv;
    pv.u = *(const unsigned*)(psrc + (size_t)t * 512 + o0);
    union { f16 h[2]; unsigned u; } pk;
    pk.h[0] = (f16)((float)pv.h[0] + v.x);
    pk.h[1] = (f16)((float)pv.h[1] + v.y);
    *(unsigned*)(pdst + (size_t)t * 512 + o0) = pk.u;
  }
}

// ---------------- gemm0: spectral GEMM both models, NPART=2, KS=128, BK=64 ----------------
__global__ __launch_bounds__(256, 2)
void k_gemm0(const f16* __restrict__ A0, const f16* __restrict__ B00,
             const float* __restrict__ aux0, f16* __restrict__ outP) {
  __shared__ __align__(16) f16 As[128 * 64];
  __shared__ __align__(16) f16 Bs[128 * 64];
  const int tid = threadIdx.x, l = tid & 63, wvi = tid >> 6;
  const int wr = wvi >> 1, wc = wvi & 1;
  int wg = (int)blockIdx.x;            // 512 = 8 * 64, bijective XCD chunk swizzle
  wg = (wg & 7) * 64 + (wg >> 3);
  const int model = wg >> 8;
  int rem = wg & 255;
  const int bz = rem >> 7; rem &= 127;
  const int by = rem >> 2, bx = rem & 3;
  const int r0 = by * 128, c0 = bx * 128;
  const f16* A  = A0  + (size_t)model * RTOT * 512;
  const f16* B0 = B00 + (size_t)model * 16384 * 512;

  f32x4 acc[4][4];
  f32x4 crun[4][4];
  f32x4 zz = {0.f, 0.f, 0.f, 0.f};
#pragma unroll
  for (int m = 0; m < 4; ++m)
#pragma unroll
    for (int n = 0; n < 4; ++n) { acc[m][n] = zz; crun[m][n] = zz; }

  const int rowl = tid >> 3;
  const int lc8 = ((tid & 7) ^ (rowl & 7)) * 8;   // swizzled chunk * 8 (f16)
  f16* lA = As + ((tid >> 6) << 9);
  f16* lB = Bs + ((tid >> 6) << 9);
  const int lr = l & 15, kg = l >> 4, sw = l & 7;

  for (int s = 0; s < 128; ++s) {
    __syncthreads();                   // prior mma's LDS reads done
    {
      const int kA = (s & 7) * 64;
      const int kb = bz * 16 + (s >> 3);
#pragma unroll
      for (int i = 0; i < 4; ++i) {
        gl16(A + (size_t)(r0 + i * 32 + rowl) * 512 + kA + lc8, lA + i * 2048);
        gl16(B0 + (size_t)(kb * 512 + c0 + i * 32 + rowl) * 512 + kA + lc8, lB + i * 2048);
      }
    }
    __syncthreads();                   // staging landed (compiler drains vmcnt)
#pragma unroll
    for (int kk = 0; kk < 2; ++kk) {
      half8 af[4], bf[4];
      const int pc8 = (((kk * 4 + kg) ^ sw) << 3);
#pragma unroll
      for (int m = 0; m < 4; ++m)
        af[m] = *(const half8*)(As + (wr * 64 + m * 16 + lr) * 64 + pc8);
#pragma unroll
      for (int n = 0; n < 4; ++n)
        bf[n] = *(const half8*)(Bs + (wc * 64 + n * 16 + lr) * 64 + pc8);
#pragma unroll
      for (int m = 0; m < 4; ++m)
#pragma unroll
        for (int n = 0; n < 4; ++n)
          acc[m][n] = __builtin_amdgcn_mfma_f32_16x16x32_f16(af[m], bf[n], acc[m][n], 0, 0, 0);
    }
    if ((s & 7) == 7) {
      int kb = bz * 16 + (s >> 3);
#pragma unroll
      for (int m = 0; m < 4; ++m) {
        int R = r0 + wr * 64 + m * 16 + (kg << 2);
        int rb = R & (RPB - 1);
        bool dc = (rb == 0);           // rows 0,1 = packed (DC.re, Nyq.re): scale separately
        float4 cs = *(const float4*)(aux0 + (size_t)kb * (CPS * 2) + (rb >> 1) * 2);
        float t1 = dc ? 0.f : cs.y;
        float t2 = dc ? cs.y : cs.x;
#pragma unroll
        for (int n = 0; n < 4; ++n) {
          f32x4 p = acc[m][n];
          crun[m][n].x += cs.x * p.x - t1 * p.y;
          crun[m][n].y += t2 * p.y + t1 * p.x;
          crun[m][n].z += cs.z * p.z - cs.w * p.w;
          crun[m][n].w += cs.z * p.w + cs.w * p.z;
          acc[m][n] = zz;
        }
      }
    }
  }

  f16* P = outP + (size_t)bz * (2ull * 512 * RTOT) + (size_t)model * 512 * RTOT;
#pragma unroll
  for (int m = 0; m < 4; ++m) {
    int R0 = r0 + wr * 64 + m * 16 + (kg << 2);
#pragma unroll
    for (int n = 0; n < 4; ++n) {
      int o = c0 + wc * 64 + n * 16 + lr;
      union { f16 h[4]; uint2 u; } pk;
      pk.h[0] = (f16)crun[m][n].x; pk.h[1] = (f16)crun[m][n].y;
      pk.h[2] = (f16)crun[m][n].z; pk.h[3] = (f16)crun[m][n].w;
      *(uint2*)(P + (size_t)o * RTOT + R0) = pk.u;
    }
  }
}

// ---------------- MLP GEMMs (modes 2,3, both models via by) ----------
template<int MODE, int MR, int NR>
__global__ __launch_bounds__(256, (MODE == 2) ? 3 : 4)
void k_gemm(const f16* __restrict__ Ain, const f16* __restrict__ Bin,
            const f16* auxAin, const f16* auxBin, f16* __restrict__ outIn) {
  __shared__ __align__(16) f16 As[MR * 32 * 64];
  __shared__ __align__(16) f16 Bs[NR * 32 * 64];
  const int tid = threadIdx.x, l = tid & 63, wvi = tid >> 6;
  const int wr = wvi >> 1, wc = wvi & 1;
  const int bx = blockIdx.x, byi = blockIdx.y;
  constexpr int BYD = (MODE == 2) ? 32 : 8;      // y-blocks per model
  const int model = byi / BYD, by = byi % BYD;
  const int r0 = by * (MR * 32), c0 = bx * (NR * 32);
  constexpr int KS = (MODE == 2) ? 8 : 32;
  const size_t actOff = (size_t)model * 2048 * 512;
  const f16* A = Ain + (size_t)model * ((MODE == 2) ? 4096ull * 512 : 512ull * 2048);
  const f16* B0 = Bin + ((MODE == 2) ? actOff : (size_t)model * 2048 * 2048);
  const f16* auxA = auxAin + actOff;
  const f16* auxB = auxBin + actOff;
  f16* outH = outIn + ((MODE == 2) ? (size_t)model * 2048 * 2048 : actOff);

  f32x4 acc[MR][NR];
  f32x4 zz = {0.f, 0.f, 0.f, 0.f};
#pragma unroll
  for (int m = 0; m < MR; ++m)
#pragma unroll
    for (int n = 0; n < NR; ++n) acc[m][n] = zz;

  for (int s = 0; s < KS; ++s) {
    __syncthreads();
    stage<MODE, MR, NR>(A, B0, r0, c0, tid, s, As, Bs);
    __syncthreads();
    mma_step<MR, NR>(As, Bs, l, wr, wc, acc);
  }

  if constexpr (MODE == 2) {
#pragma unroll
    for (int m = 0; m < MR; ++m) {
      int jj0 = r0 + wr * (MR * 16) + m * 16 + ((l >> 4) << 2);
      int h2 = jj0 >> 1;
#pragma unroll
      for (int n = 0; n < NR; ++n) {
        int r = c0 + wc * (NR * 16) + n * 16 + (l & 15);
        f32x4 a = acc[m][n];
        float v0 = a.x * (a.y / (1.f + __expf(-a.y)));
        float v1 = a.z * (a.w / (1.f + __expf(-a.w)));
        union { f16 h[2]; unsigned u; } pk;
        pk.h[0] = (f16)v0; pk.h[1] = (f16)v1;
        *(unsigned*)(outH + (size_t)r * 2048 + h2) = pk.u;
      }
    }
  } else {
#pragma unroll
    for (int m = 0; m < MR; ++m) {
      int o0 = r0 + wr * (MR * 16) + m * 16 + ((l >> 4) << 2);
#pragma unroll
      for (int n = 0; n < NR; ++n) {
        int r = c0 + wc * (NR * 16) + n * 16 + (l & 15);
        union { uint2 u; f16 h[4]; } xv, x1v;
        xv.u  = *(const uint2*)(auxA + (size_t)r * 512 + o0);
        x1v.u = *(const uint2*)(auxB + (size_t)r * 512 + o0);
        f32x4 a = acc[m][n];
        union { f16 h[4]; uint2 u; } pk;
        pk.h[0] = (f16)((float)xv.h[0] + (float)x1v.h[0] + a.x);
        pk.h[1] = (f16)((float)xv.h[1] + (float)x1v.h[1] + a.y);
        pk.h[2] = (f16)((float)xv.h[2] + (float)x1v.h[2] + a.z);
        pk.h[3] = (f16)((float)xv.h[3] + (float)x1v.h[3] + a.w);
        *(uint2*)(outH + (size_t)r * 512 + o0) = pk.u;
      }
    }
  }
}

// ---------------- inproj (0..4095) + Wu cast for all 4 model-layers (4096..4863) ----------
__global__ __launch_bounds__(256)
void k_inproj(const float* __restrict__ inp, const float* __restrict__ Wall,
              const float* __restrict__ Mu, f16* __restrict__ x, f16* __restrict__ WuAll) {
  __shared__ __align__(16) char smem[16900];
  int wg = (int)blockIdx.x, tid = threadIdx.x;
  if (wg < 4096) {
    float* row = (float*)smem;
    int r = wg;
    int model = r >> 11, rl = r & 2047;
    const float* W = Wall + (size_t)model * 512 * 64;
    if (tid < 64) row[tid] = inp[(size_t)rl * 64 + tid];
    __syncthreads();
    for (int o = tid; o < 512; o += 256) {
      const float* wr = W + (size_t)o * 64;
      float acc = 0.f;
#pragma unroll 8
      for (int q = 0; q < 64; ++q) acc += row[q] * wr[q];
      x[(size_t)r * 512 + o] = (f16)acc;
    }
    return;
  }
  // Wu cast: Wu[li][model][o][ip*512+d] = mu[ml][2-ip][d][o]
  float* T = (float*)smem;
  int q = wg - 4096;                   // 0..767
  int lm = q & 3;
  int model = lm & 1, li = lm >> 1;
  int blk = q >> 2;                    // 0..191
  int ip = blk >> 6, tile = blk & 63;
  int d0 = (tile >> 3) * 64, o0 = (tile & 7) * 64;
  const float* src = Mu + ((size_t)(model * 2 + li) * 3 + (2 - ip)) * 262144;
  f16* dst = WuAll + ((size_t)li * 2 + model) * (512ull * 1536);
  for (int p = tid; p < 4096; p += 256) {
    int i = p >> 6, j = p & 63;
    T[i * 65 + j] = src[(size_t)(d0 + i) * 512 + o0 + j];
  }
  __syncthreads();
  for (int p = tid; p < 4096; p += 256) {
    int i = p >> 6, j = p & 63;
    dst[(size_t)(o0 + i) * 1536 + ip * 512 + d0 + j] = (f16)T[j * 65 + i];
  }
}

// out[r] = x_m0[r] @ W0^T + x_m1[r] @ W1^T  (single kernel, both models)
__global__ void k_outproj(const f16* __restrict__ x, const float* __restrict__ Wall,
                          float* out) {
  __shared__ float row[1024];
  int r = blockIdx.x, tid = threadIdx.x;
  for (int i = tid; i < 1024; i += 256) {
    int mdl = i >> 9, c = i & 511;
    row[i] = (float)x[((size_t)mdl * 2048 + r) * 512 + c];
  }
  __syncthreads();
  int o = tid >> 2, part = tid & 3;
  const float* w0 = Wall + (size_t)o * 512 + part * 128;
  const float* w1 = Wall + 64ull * 512 + (size_t)o * 512 + part * 128;
  const float* r0 = row + part * 128;
  const float* r1 = row + 512 + part * 128;
  float acc = 0.f;
#pragma unroll 16
  for (int q = 0; q < 128; ++q) acc += r0[q] * w0[q] + r1[q] * w1[q];
  acc += __shfl_xor(acc, 1, 64);
  acc += __shfl_xor(acc, 2, 64);
  if (part == 0) out[(size_t)r * 64 + o] = acc;
}

// ---------------- host ----------------
extern "C" void kernel_launch(void* const* d_in, const int* in_sizes, int n_in,
                              void* d_out, int out_size, void* d_ws, size_t ws_size,
                              hipStream_t stream) {
  const float* inputs    = (const float*)d_in[0];
  const float* sigma     = (const float*)d_in[1];
  const float* phi       = (const float*)d_in[2];
  const float* in_proj_w = (const float*)d_in[3];
  const float* rn_w      = (const float*)d_in[4];
  const float* M_u       = (const float*)d_in[5];
  const float* M_phi_p   = (const float*)d_in[6];
  const float* M_phi_m   = (const float*)d_in[7];
  const float* fc1       = (const float*)d_in[8];
  const float* fc2       = (const float*)d_in[9];
  const float* out_proj_w= (const float*)d_in[10];
  float* out = (float*)d_out;

  char* ws = (char*)d_ws;
  size_t off = 0;
  auto alloc = [&](size_t bytes) -> void* {
    void* p = ws + off;
    off += (bytes + 255) & ~(size_t)255;
    return p;
  };
  float2* tw   = (float2*)alloc(1024 * 8);
  float2* Vf   = (float2*)alloc((size_t)16 * 1025 * 8);
  float2* cpcm = (float2*)alloc((size_t)32 * CPS * 8);
  f16*    x    = (f16*)alloc((size_t)2 * NROW * 512 * 2);
  f16*    hb2  = (f16*)alloc((size_t)4 * 1026 * 512 * 2);   // 2 models x 2 batches
  f16*    x1p  = (f16*)alloc((size_t)2 * NROW * 512 * 2);
  f16*    x1   = (f16*)alloc((size_t)2 * NROW * 512 * 2);
  f16*    Xbf  = (f16*)alloc((size_t)2 * RTOT * 512 * 2);
  f16*    P    = (f16*)alloc((size_t)NPART * 2 * 512 * RTOT * 2);
  f16*    g1   = (f16*)alloc((size_t)2 * NROW * 2048 * 2);
  f16*    Wsp  = (f16*)alloc((size_t)2 * 16384 * 512 * 2);
  f16*    WuA  = (f16*)alloc((size_t)4 * 512 * 1536 * 2);   // [li][model]
  f16*    Wf1  = (f16*)alloc((size_t)2 * 4096 * 512 * 2);
  f16*    Wf2  = (f16*)alloc((size_t)2 * 512 * 2048 * 2);
  if (off > ws_size) return;  // workspace too small: fail loudly (output stays poisoned)

  // zero the AR window pad rows (rows 0,1 of each of the 4 batch blocks)
  for (int k = 0; k < 4; ++k)
    hipMemsetAsync(hb2 + (size_t)k * 1026 * 512, 0, 2 * 512 * sizeof(f16), stream);
  k_twiddle<<<4, 256, 0, stream>>>(tw);
  k_fft_phi<<<8, 256, 0, stream>>>(phi, Vf, tw);
  k_cpcm<<<133, 256, 0, stream>>>(Vf, sigma, cpcm);

  k_inproj<<<4096 + 768, 256, 0, stream>>>(inputs, in_proj_w, M_u, x, WuA);
  for (int li = 0; li < 2; ++li) {
    k_rmsnorm<<<1024, 256, 0, stream>>>(x, rn_w, li, hb2);
    k_fwdcast<<<1024 + 512 + 7168, 256, 0, stream>>>(
        hb2, Xbf, tw, li, M_phi_p, M_phi_m, fc1, fc2, Wsp, WuA, Wf1, Wf2, x, x1p);
    k_gemm0<<<dim3(512), 256, 0, stream>>>(Xbf, Wsp, (const float*)cpcm, P);
    k_fft_inv<<<1024, 256, 0, stream>>>(P, x1p, x1, tw);
    k_gemm<2, 4, 4><<<dim3(16, 64), 256, 0, stream>>>(Wf1, x1, nullptr, nullptr, g1);
    k_gemm<3, 2, 2><<<dim3(32, 16), 256, 0, stream>>>(Wf2, g1, x, x1, x);
  }
  k_outproj<<<NROW, 256, 0, stream>>>(x, out_proj_w, out);
}

// Round 16
// 737.391 us; speedup vs baseline: 1.1234x; 1.0159x over previous
//
#include <hip/hip_runtime.h>
#include <hip/hip_bf16.h>

typedef _Float16 f16;
typedef _Float16 half8 __attribute__((ext_vector_type(8)));
typedef float f32x4 __attribute__((ext_vector_type(4)));

#define S_LEN 1024
#define DMODEL 512
#define NFFT   2048
#define RPB    2048     // rows per batch: f=1..1023 pairs + packed (DC.re, Nyq.re) in rows 0,1
#define RTOT   4096     // per-model: 2 batches -> exactly 32 row-tiles of 128
#define CPS    1064     // cpcm f-stride
#define NROW   2048     // B*S per model
#define NPART  2        // split-K partials (gemm0 grid 512 = exactly 1 generation)

__device__ __forceinline__ float2 mkf2(float a, float b) { float2 r; r.x = a; r.y = b; return r; }
__device__ __forceinline__ int zp(int i) { return i + (i >> 5); }   // LDS bank-pad for FFT array
__device__ __forceinline__ float2 cmul(float2 w, float2 b) {
  return mkf2(b.x * w.x - b.y * w.y, b.x * w.y + b.y * w.x);
}
__device__ __forceinline__ float2 f2a(float2 a, float2 b) { return mkf2(a.x + b.x, a.y + b.y); }
__device__ __forceinline__ float2 f2s(float2 a, float2 b) { return mkf2(a.x - b.x, a.y - b.y); }

// async global->LDS (16B per lane). LDS dest must be wave-uniform base; lane writes at +lane*16.
__device__ __forceinline__ void gl16(const f16* g, f16* l) {
  __builtin_amdgcn_global_load_lds((const __attribute__((address_space(1))) void*)g,
                                   (__attribute__((address_space(3))) void*)l, 16, 0, 0);
}

// ---------------- FFT-2048 in LDS: 3x radix-8 + 1x radix-4, padded indexing ----------------
template<bool INV>
__device__ __forceinline__ void fft2048(float2* z, const float2* __restrict__ tw, int tid) {
  for (int i = tid; i < 2048; i += 256) {
    int j = (int)(__brev((unsigned)i) >> 21);
    if (i < j) { float2 a = z[zp(i)]; z[zp(i)] = z[zp(j)]; z[zp(j)] = a; }
  }
  __syncthreads();
#pragma unroll
  for (int r8 = 0; r8 < 3; ++r8) {       // fused stages (1,2,3),(4,5,6),(7,8,9)
    const int sl = 1 + 3 * r8;
    const int h = 1 << (sl - 1);
    {
      int q = tid;                        // 256 groups of 8, one per thread
      int j = q & (h - 1);
      int i0 = ((q >> (sl - 1)) << (sl + 2)) + j;
      float2 a0 = z[zp(i0)],         a1 = z[zp(i0 + h)];
      float2 a2 = z[zp(i0 + 2 * h)], a3 = z[zp(i0 + 3 * h)];
      float2 a4 = z[zp(i0 + 4 * h)], a5 = z[zp(i0 + 5 * h)];
      float2 a6 = z[zp(i0 + 6 * h)], a7 = z[zp(i0 + 7 * h)];
      float2 wA  = tw[j << (11 - sl)];
      float2 wB0 = tw[j << (10 - sl)];
      float2 wB1 = tw[(j + h) << (10 - sl)];
      float2 wC0 = tw[j << (9 - sl)];
      float2 wC1 = tw[(j + h) << (9 - sl)];
      float2 wC2 = tw[(j + 2 * h) << (9 - sl)];
      float2 wC3 = tw[(j + 3 * h) << (9 - sl)];
      if (INV) {
        wA.y = -wA.y; wB0.y = -wB0.y; wB1.y = -wB1.y;
        wC0.y = -wC0.y; wC1.y = -wC1.y; wC2.y = -wC2.y; wC3.y = -wC3.y;
      }
      float2 t;
      t = cmul(wA, a1); float2 b0 = f2a(a0, t), b1 = f2s(a0, t);
      t = cmul(wA, a3); float2 b2 = f2a(a2, t), b3 = f2s(a2, t);
      t = cmul(wA, a5); float2 b4 = f2a(a4, t), b5 = f2s(a4, t);
      t = cmul(wA, a7); float2 b6 = f2a(a6, t), b7 = f2s(a6, t);
      t = cmul(wB0, b2); float2 c0 = f2a(b0, t), c2 = f2s(b0, t);
      t = cmul(wB1, b3); float2 c1 = f2a(b1, t), c3 = f2s(b1, t);
      t = cmul(wB0, b6); float2 c4 = f2a(b4, t), c6 = f2s(b4, t);
      t = cmul(wB1, b7); float2 c5 = f2a(b5, t), c7 = f2s(b5, t);
      t = cmul(wC0, c4); z[zp(i0)]         = f2a(c0, t); z[zp(i0 + 4 * h)] = f2s(c0, t);
      t = cmul(wC1, c5); z[zp(i0 + h)]     = f2a(c1, t); z[zp(i0 + 5 * h)] = f2s(c1, t);
      t = cmul(wC2, c6); z[zp(i0 + 2 * h)] = f2a(c2, t); z[zp(i0 + 6 * h)] = f2s(c2, t);
      t = cmul(wC3, c7); z[zp(i0 + 3 * h)] = f2a(c3, t); z[zp(i0 + 7 * h)] = f2s(c3, t);
    }
    __syncthreads();
  }
  for (int q = tid; q < 512; q += 256) {  // final radix-4 round: stages (10,11)
    float2 a0 = z[zp(q)], a1 = z[zp(q + 512)], a2 = z[zp(q + 1024)], a3 = z[zp(q + 1536)];
    float2 w1 = tw[q << 1], w2 = tw[q], w3 = tw[q + 512];
    if (INV) { w1.y = -w1.y; w2.y = -w2.y; w3.y = -w3.y; }
    float2 t;
    t = cmul(w1, a1); float2 b0 = f2a(a0, t), b1 = f2s(a0, t);
    t = cmul(w1, a3); float2 b2 = f2a(a2, t), b3 = f2s(a2, t);
    t = cmul(w2, b2); z[zp(q)]        = f2a(b0, t); z[zp(q + 1024)] = f2s(b0, t);
    t = cmul(w3, b3); z[zp(q + 512)]  = f2a(b1, t); z[zp(q + 1536)] = f2s(b1, t);
  }
  __syncthreads();
}

// ---------------- init kernels ----------------
__global__ void k_twiddle(float2* tw) {
  int i = blockIdx.x * 256 + threadIdx.x;
  if (i < 1024) {
    float ang = -6.2831853071795864769f * (float)i / 2048.0f;
    tw[i] = mkf2(cosf(ang), sinf(ang));
  }
}

// rfft of phi columns (pairs packed into one complex FFT)
__global__ void k_fft_phi(const float* __restrict__ phi, float2* __restrict__ Vf,
                          const float2* __restrict__ tw) {
  __shared__ float2 z[2112];
  int tid = threadIdx.x;
  int k0 = blockIdx.x * 2;
  for (int t = tid; t < 1024; t += 256)
    z[zp(t)] = *(const float2*)(phi + (size_t)t * 16 + k0);
  for (int t = 1024 + tid; t < 2048; t += 256) z[zp(t)] = mkf2(0.f, 0.f);
  __syncthreads();
  fft2048<false>(z, tw, tid);
  for (int f = tid; f <= 1024; f += 256) {
    float2 zf = z[zp(f)], zc = z[zp((2048 - f) & 2047)];
    Vf[(size_t)k0 * 1025 + f]       = mkf2(0.5f * (zf.x + zc.x), 0.5f * (zf.y - zc.y));
    Vf[(size_t)(k0 + 1) * 1025 + f] = mkf2(0.5f * (zf.y + zc.y), 0.5f * (zc.x - zf.x));
  }
}

// cpcm[kb][f]: f=1..1023 standard complex scale; slot 0 packs (c_DC, c_Nyq) (both REAL).
__global__ void k_cpcm(const float2* __restrict__ Vf, const float* __restrict__ sigma,
                       float2* __restrict__ cpcm) {
  int idx = blockIdx.x * 256 + threadIdx.x;
  if (idx >= 32 * CPS) return;
  int kb = idx / CPS, f = idx - kb * CPS;
  int k = kb & 15;
  float s = powf(sigma[k], 0.25f) * (1.0f / 2048.0f);
  float2 v = mkf2(0.f, 0.f);
  if (f == 0) {
    float dc = Vf[(size_t)k * 1025].x;          // real
    float ny = Vf[(size_t)k * 1025 + 1024].x;   // real
    v = (kb < 16) ? mkf2(s * dc, s * ny) : mkf2(s * ny, s * dc);
  } else if (f <= 1023) {
    if (kb < 16) {
      v = Vf[(size_t)k * 1025 + f];
    } else {
      float2 t = Vf[(size_t)k * 1025 + (1024 - f)];
      v = mkf2(t.x, -t.y);
    }
    v.x *= s; v.y *= s;
  }
  cpcm[idx] = v;
}

// ---------------- generic GEMM helpers (BK=64) ----------------
template<int MODE, int MR, int NR>
__device__ __forceinline__ void stage(const f16* __restrict__ A, const f16* __restrict__ B0,
                                      int r0, int c0, int tid, int s,
                                      f16* As, f16* Bs) {
  constexpr int LDA = (MODE == 1) ? 1536 : (MODE == 2) ? 512 : 2048;
  const int kA = s * 64;
  const int rowl = tid >> 3;
  const int lc8 = ((tid & 7) ^ (rowl & 7)) * 8;   // swizzled chunk * 8 (f16)
  f16* lA = As + ((tid >> 6) << 9);
  f16* lB = Bs + ((tid >> 6) << 9);
#pragma unroll
  for (int i = 0; i < MR; ++i) {
    int row = i * 32 + rowl;
    gl16(A + (size_t)(r0 + row) * LDA + kA + lc8, lA + i * 2048);
  }
#pragma unroll
  for (int i = 0; i < NR; ++i) {
    int row = i * 32 + rowl;
    const f16* bs;
    if constexpr (MODE == 1) {
      int ip = s >> 3, d0 = (s & 7) * 64;
      int rr = c0 + row;
      int b = rr >> 10, t = rr & 1023;
      bs = B0 + (size_t)(b * 1026 + t + ip) * 512 + d0 + lc8;   // pad rows are zero
    } else {
      constexpr int LDB = (MODE == 2) ? 512 : 2048;
      bs = B0 + (size_t)(c0 + row) * LDB + s * 64 + lc8;
    }
    gl16(bs, lB + i * 2048);
  }
}

template<int MR, int NR>
__device__ __forceinline__ void mma_step(const f16* As, const f16* Bs, int l, int wr, int wc,
                                         f32x4 acc[MR][NR]) {
  const int lr = l & 15, kg = l >> 4, sw = l & 7;
#pragma unroll
  for (int kk = 0; kk < 2; ++kk) {
    half8 af[MR], bf[NR];
    const int pc8 = (((kk * 4 + kg) ^ sw) << 3);
#pragma unroll
    for (int m = 0; m < MR; ++m)
      af[m] = *(const half8*)(As + (wr * (MR * 16) + m * 16 + lr) * 64 + pc8);
#pragma unroll
    for (int n = 0; n < NR; ++n)
      bf[n] = *(const half8*)(Bs + (wc * (NR * 16) + n * 16 + lr) * 64 + pc8);
#pragma unroll
    for (int m = 0; m < MR; ++m)
#pragma unroll
      for (int n = 0; n < NR; ++n)
        acc[m][n] = __builtin_amdgcn_mfma_f32_16x16x32_f16(af[m], bf[n], acc[m][n], 0, 0, 0);
  }
}

// ---------------- merged per-layer: fwd FFT (0..1023) + AR gemm1 (1024..1535) + cast ----------
// All three depend only on prior-launch outputs (hb2, x, pre-cast Wu) -> safe same-launch merge.
// gemm1 writes x1p = x + AR(h); spec is added later inside fft_inv.
__global__ __launch_bounds__(256)
void k_fwdcast(const f16* __restrict__ hb2, f16* __restrict__ Xbf,
               const float2* __restrict__ tw, int li,
               const float* __restrict__ Mp, const float* __restrict__ Mm,
               const float* __restrict__ Fc1, const float* __restrict__ Fc2,
               f16* __restrict__ Wsp, const f16* __restrict__ WuAll,
               f16* __restrict__ Wf1, f16* __restrict__ Wf2,
               const f16* __restrict__ x, f16* __restrict__ x1p) {
  __shared__ __align__(16) char smem[16896];
  int wg = (int)blockIdx.x, tid = threadIdx.x;
  if (wg < 1024) {
    // ---- forward FFT of hb2 -> Xbf; rows 0,1 = (DC.re, Nyq.re), rows 2f,2f+1 f=1..1023
    float2* z = (float2*)smem;
    int model = wg >> 9;
    int b = (wg >> 8) & 1;
    int d0 = (wg & 255) * 2;
    const f16* hsrc = hb2 + (size_t)(model * 2 + b) * 1026 * 512;
    f16* xdst = Xbf + (size_t)model * RTOT * 512 + (size_t)b * RPB * 512;
    for (int t = tid; t < 1024; t += 256) {
      union { unsigned v; f16 q[2]; } w;
      w.v = *(const unsigned*)(hsrc + (size_t)(2 + t) * 512 + d0);
      z[zp(t)] = mkf2((float)w.q[0], (float)w.q[1]);
    }
    for (int t = 1024 + tid; t < 2048; t += 256) z[zp(t)] = mkf2(0.f, 0.f);
    __syncthreads();
    fft2048<false>(z, tw, tid);
    for (int f = tid; f <= 1024; f += 256) {
      float2 zf = z[zp(f)], zc = z[zp((2048 - f) & 2047)];
      float x0r = 0.5f * (zf.x + zc.x), x0i = 0.5f * (zf.y - zc.y);
      float x1r = 0.5f * (zf.y + zc.y), x1i = 0.5f * (zc.x - zf.x);
      union { f16 h2[2]; unsigned u; } pr, pi;
      pr.h2[0] = (f16)x0r; pr.h2[1] = (f16)x1r;
      pi.h2[0] = (f16)x0i; pi.h2[1] = (f16)x1i;
      if (f == 0) {
        *(unsigned*)(xdst + d0) = pr.u;                                  // DC (im=0)
      } else if (f == 1024) {
        *(unsigned*)(xdst + (size_t)512 + d0) = pr.u;                    // Nyquist (im=0)
      } else {
        *(unsigned*)(xdst + (size_t)(2 * f) * 512 + d0)     = pr.u;
        *(unsigned*)(xdst + (size_t)(2 * f + 1) * 512 + d0) = pi.u;
      }
    }
    return;
  }
  if (wg < 1536) {
    // ---- AR gemm1 (MODE 1): x1p = x + AR(h), 64x64 tiles, KS=24
    f16* As = (f16*)smem;
    f16* Bs = (f16*)smem + 4096;
    int q = wg - 1024;
    const int bx = q & 31, byi = q >> 5;
    const int model = byi >> 3, by = byi & 7;
    const int r0 = by * 64, c0 = bx * 64;
    const int l = tid & 63, wvi = tid >> 6;
    const int wr = wvi >> 1, wc = wvi & 1;
    const f16* A  = WuAll + ((size_t)li * 2 + model) * (512ull * 1536);
    const f16* B0 = hb2 + (size_t)model * 2 * 1026 * 512;
    const f16* xM  = x  + (size_t)model * 2048 * 512;
    f16* x1pM      = x1p + (size_t)model * 2048 * 512;

    f32x4 acc[2][2];
    f32x4 zz = {0.f, 0.f, 0.f, 0.f};
#pragma unroll
    for (int m = 0; m < 2; ++m)
#pragma unroll
      for (int n = 0; n < 2; ++n) acc[m][n] = zz;

    for (int s = 0; s < 24; ++s) {
      __syncthreads();
      stage<1, 2, 2>(A, B0, r0, c0, tid, s, As, Bs);
      __syncthreads();
      mma_step<2, 2>(As, Bs, l, wr, wc, acc);
    }
#pragma unroll
    for (int m = 0; m < 2; ++m) {
      int o0 = r0 + wr * 32 + m * 16 + ((l >> 4) << 2);
#pragma unroll
      for (int n = 0; n < 2; ++n) {
        int r = c0 + wc * 32 + n * 16 + (l & 15);
        union { uint2 u; f16 h[4]; } xv;
        xv.u = *(const uint2*)(xM + (size_t)r * 512 + o0);
        f32x4 a = acc[m][n];
        union { f16 h[4]; uint2 u; } pk;
        pk.h[0] = (f16)((float)xv.h[0] + a.x);
        pk.h[1] = (f16)((float)xv.h[1] + a.y);
        pk.h[2] = (f16)((float)xv.h[2] + a.z);
        pk.h[3] = (f16)((float)xv.h[3] + a.w);
        *(uint2*)(x1pM + (size_t)r * 512 + o0) = pk.u;
      }
    }
    return;
  }
  // ---- weight cast/transpose for BOTH models (Wsp, fc1, fc2), T[64][65] in smem
  float* T = (float*)smem;
  int q0all = wg - 1536;               // 0..7167
  int model = q0all & 1;
  int blk = q0all >> 1;                // 0..3583
  int ml = model * 2 + li;
  const float* mp  = Mp  + (size_t)ml * 16 * 262144;
  const float* mm  = Mm  + (size_t)ml * 16 * 262144;
  const float* fc1 = Fc1 + (size_t)ml * 4096 * 512;
  const float* fc2 = Fc2 + (size_t)ml * 512 * 2048;
  f16* WspM = Wsp + (size_t)model * 16384 * 512;
  f16* Wf1M = Wf1 + (size_t)model * 4096 * 512;
  f16* Wf2M = Wf2 + (size_t)model * 512 * 2048;
  if (blk < 2048) {                    // Wsp: Wsp[(kb*512+o)][d] = m?[k][d][o]
    int mat = blk >> 6, tile = blk & 63;
    int d0 = (tile >> 3) * 64, o0 = (tile & 7) * 64;
    const float* src = (mat < 16) ? (mp + (size_t)mat * 262144)
                                  : (mm + (size_t)(mat - 16) * 262144);
    for (int q = tid; q < 4096; q += 256) {
      int i = q >> 6, j = q & 63;
      T[i * 65 + j] = src[(size_t)(d0 + i) * 512 + o0 + j];
    }
    __syncthreads();
    for (int q = tid; q < 4096; q += 256) {
      int i = q >> 6, j = q & 63;
      WspM[(size_t)(mat * 512 + o0 + i) * 512 + d0 + j] = (f16)T[j * 65 + i];
    }
  } else if (blk < 3072) {             // fc1 perm copy: row 2h = y-row h, 2h+1 = gate-row h
    int q1 = blk - 2048;
    size_t e = ((size_t)q1 * 256 + tid) * 8;
    int jj = (int)(e >> 9), col = (int)(e & 511);
    int srow = (jj & 1) ? (2048 + (jj >> 1)) : (jj >> 1);
    const float4* s = (const float4*)(fc1 + (size_t)srow * 512 + col);
    float4 a = s[0], b = s[1];
    union { f16 h[8]; uint4 u; } pk;
    pk.h[0] = (f16)a.x; pk.h[1] = (f16)a.y; pk.h[2] = (f16)a.z; pk.h[3] = (f16)a.w;
    pk.h[4] = (f16)b.x; pk.h[5] = (f16)b.y; pk.h[6] = (f16)b.z; pk.h[7] = (f16)b.w;
    *(uint4*)(Wf1M + (size_t)jj * 512 + col) = pk.u;
  } else {                             // fc2 straight copy (already [o][j])
    int q1 = blk - 3072;
    size_t e = ((size_t)q1 * 256 + tid) * 8;
    const float4* s = (const float4*)(fc2 + e);
    float4 a = s[0], b = s[1];
    union { f16 h[8]; uint4 u; } pk;
    pk.h[0] = (f16)a.x; pk.h[1] = (f16)a.y; pk.h[2] = (f16)a.z; pk.h[3] = (f16)a.w;
    pk.h[4] = (f16)b.x; pk.h[5] = (f16)b.y; pk.h[6] = (f16)b.z; pk.h[7] = (f16)b.w;
    *(uint4*)(Wf2M + e) = pk.u;
  }
}

// ---------------- rmsnorm both models (grid 1024) ----------------
__global__ void k_rmsnorm(const f16* __restrict__ x, const float* __restrict__ rn_w, int li,
                          f16* __restrict__ hb2) {
  int tid = threadIdx.x, l = tid & 63, wv = tid >> 6;
  int r = blockIdx.x * 4 + wv;           // 0..4095 global row
  int model = r >> 11;
  int rl = r & 2047;
  int b = rl >> 10, t = rl & 1023;
  const float* w = rn_w + (size_t)(model * 2 + li) * 512;
  const f16* xr = x + (size_t)r * 512;
  f16* hr = hb2 + (size_t)((model * 2 + b) * 1026 + 2 + t) * 512;
  float v[8]; float ss = 0.f;
#pragma unroll
  for (int j = 0; j < 8; ++j) { v[j] = (float)xr[j * 64 + l]; ss += v[j] * v[j]; }
#pragma unroll
  for (int o = 32; o; o >>= 1) ss += __shfl_xor(ss, o, 64);
  float rn = rsqrtf(ss * (1.f / 512.f) + 1e-5f);
#pragma unroll
  for (int j = 0; j < 8; ++j) {
    float hv = v[j] * rn * w[j * 64 + l];
    hr[j * 64 + l] = (f16)hv;
  }
}

// ---------------- inverse FFT both models: sum NPART partials, fuse x1 = x1p + spec ----------
__global__ void k_fft_inv(const f16* __restrict__ P, const f16* __restrict__ x1p,
                          f16* __restrict__ x1, const float2* __restrict__ tw) {
  __shared__ float2 z[2112];
  int tid = threadIdx.x;
  int wg = (int)blockIdx.x;
  int model = wg >> 9;
  int b = (wg >> 8) & 1;
  int o0 = (wg & 255) * 2;
  const f16* Pm = P + (size_t)model * 512 * RTOT;
  for (int fp = tid; fp < 512; fp += 256) {
    int f0 = fp * 2;
    size_t base0 = (size_t)o0 * RTOT + (size_t)b * RPB + 2 * f0;
    float s0r[2] = {0.f, 0.f}, s0i[2] = {0.f, 0.f};
    float s1r[2] = {0.f, 0.f}, s1i[2] = {0.f, 0.f};
#pragma unroll
    for (int g = 0; g < NPART; ++g) {
      const f16* Pg = Pm + (size_t)g * (2ull * 512 * RTOT);
      union { uint2 u; f16 h[4]; } ua, uc;
      ua.u = *(const uint2*)(Pg + base0);
      uc.u = *(const uint2*)(Pg + base0 + RTOT);
      s0r[0] += (float)ua.h[0]; s0i[0] += (float)ua.h[1];
      s0r[1] += (float)ua.h[2]; s0i[1] += (float)ua.h[3];
      s1r[0] += (float)uc.h[0]; s1i[0] += (float)uc.h[1];
      s1r[1] += (float)uc.h[2]; s1i[1] += (float)uc.h[3];
    }
    if (fp == 0) {
      z[zp(0)]    = mkf2(s0r[0], s1r[0]);   // DC of both real o-channels
      z[zp(1024)] = mkf2(s0i[0], s1i[0]);   // Nyquist of both
    } else {
      z[zp(f0)]        = mkf2(s0r[0] - s1i[0], s0i[0] + s1r[0]);
      z[zp(2048 - f0)] = mkf2(s0r[0] + s1i[0], s1r[0] - s0i[0]);
    }
    int f1 = f0 + 1;
    z[zp(f1)]        = mkf2(s0r[1] - s1i[1], s0i[1] + s1r[1]);
    z[zp(2048 - f1)] = mkf2(s0r[1] + s1i[1], s1r[1] - s0i[1]);
  }
  __syncthreads();
  fft2048<true>(z, tw, tid);
  size_t rowOff = (size_t)(model * 2048 + b * 1024) * 512;
  const f16* psrc = x1p + rowOff;
  f16* pdst = x1 + rowOff;
  for (int t = tid; t < 1024; t += 256) {
    float2 v = z[zp(t)];
    union { unsigned u; f16 h[2]; } pv;
    pv.u = *(const unsigned*)(psrc + (size_t)t * 512 + o0);
    union { f16 h[2]; unsigned u; } pk;
    pk.h[0] = (f16)((float)pv.h[0] + v.x);
    pk.h[1] = (f16)((float)pv.h[1] + v.y);
    *(unsigned*)(pdst + (size_t)t * 512 + o0) = pk.u;
  }
}

// ---------------- gemm0: spectral GEMM both models, NPART=2, super-steps of BK=128 ----------
// Two independent 64-wide LDS tiles per super-step, each with the proven conflict-free
// 8-chunk swizzle (r13's single 128-wide tile had 8.4M conflicts). Halves barrier count
// vs r15 while keeping identical per-half LDS access patterns. kb constant per super-step.
__global__ __launch_bounds__(256, 2)
void k_gemm0(const f16* __restrict__ A0, const f16* __restrict__ B00,
             const float* __restrict__ aux0, f16* __restrict__ outP) {
  __shared__ __align__(16) f16 As[2][128 * 64];
  __shared__ __align__(16) f16 Bs[2][128 * 64];
  const int tid = threadIdx.x, l = tid & 63, wvi = tid >> 6;
  const int wr = wvi >> 1, wc = wvi & 1;
  int wg = (int)blockIdx.x;            // 512 = 8 * 64, bijective XCD chunk swizzle
  wg = (wg & 7) * 64 + (wg >> 3);
  const int model = wg >> 8;
  int rem = wg & 255;
  const int bz = rem >> 7; rem &= 127;
  const int by = rem >> 2, bx = rem & 3;
  const int r0 = by * 128, c0 = bx * 128;
  const f16* A  = A0  + (size_t)model * RTOT * 512;
  const f16* B0 = B00 + (size_t)model * 16384 * 512;

  f32x4 acc[4][4];
  f32x4 crun[4][4];
  f32x4 zz = {0.f, 0.f, 0.f, 0.f};
#pragma unroll
  for (int m = 0; m < 4; ++m)
#pragma unroll
    for (int n = 0; n < 4; ++n) { acc[m][n] = zz; crun[m][n] = zz; }

  const int rowl = tid >> 3;
  const int lc8 = ((tid & 7) ^ (rowl & 7)) * 8;   // swizzled chunk * 8 (f16)
  const int wvOff = (tid >> 6) << 9;
  const int lr = l & 15, kg = l >> 4, sw = l & 7;

  for (int ss = 0; ss < 64; ++ss) {    // super-step = 2 BK=64 steps, same kb
    __syncthreads();                   // prior mma's LDS reads done
    {
      const int s0 = ss * 2;
      const int kb = bz * 16 + (ss >> 2);
      const f16* Abase = A + (size_t)(r0 + rowl) * 512 + lc8;
      const f16* Bbase = B0 + (size_t)(kb * 512 + c0 + rowl) * 512 + lc8;
#pragma unroll
      for (int h = 0; h < 2; ++h) {
        const int kA = ((s0 + h) & 7) * 64;
        f16* lA = As[h] + wvOff;
        f16* lB = Bs[h] + wvOff;
#pragma unroll
        for (int i = 0; i < 4; ++i) {
          gl16(Abase + (size_t)(i * 32) * 512 + kA, lA + i * 2048);
          gl16(Bbase + (size_t)(i * 32) * 512 + kA, lB + i * 2048);
        }
      }
    }
    __syncthreads();                   // staging landed (compiler drains vmcnt)
#pragma unroll
    for (int h = 0; h < 2; ++h) {
#pragma unroll
      for (int kk = 0; kk < 2; ++kk) {
        half8 af[4], bf[4];
        const int pc8 = (((kk * 4 + kg) ^ sw) << 3);
#pragma unroll
        for (int m = 0; m < 4; ++m)
          af[m] = *(const half8*)(As[h] + (wr * 64 + m * 16 + lr) * 64 + pc8);
#pragma unroll
        for (int n = 0; n < 4; ++n)
          bf[n] = *(const half8*)(Bs[h] + (wc * 64 + n * 16 + lr) * 64 + pc8);
#pragma unroll
        for (int m = 0; m < 4; ++m)
#pragma unroll
          for (int n = 0; n < 4; ++n)
            acc[m][n] = __builtin_amdgcn_mfma_f32_16x16x32_f16(af[m], bf[n], acc[m][n], 0, 0, 0);
      }
    }
    if ((ss & 3) == 3) {               // per-kb complex rescale into running sum
      int kb = bz * 16 + (ss >> 2);
#pragma unroll
      for (int m = 0; m < 4; ++m) {
        int R = r0 + wr * 64 + m * 16 + (kg << 2);
        int rb = R & (RPB - 1);
        bool dc = (rb == 0);           // rows 0,1 = packed (DC.re, Nyq.re): scale separately
        float4 cs = *(const float4*)(aux0 + (size_t)kb * (CPS * 2) + (rb >> 1) * 2);
        float t1 = dc ? 0.f : cs.y;
        float t2 = dc ? cs.y : cs.x;
#pragma unroll
        for (int n = 0; n < 4; ++n) {
          f32x4 p = acc[m][n];
          crun[m][n].x += cs.x * p.x - t1 * p.y;
          crun[m][n].y += t2 * p.y + t1 * p.x;
          crun[m][n].z += cs.z * p.z - cs.w * p.w;
          crun[m][n].w += cs.z * p.w + cs.w * p.z;
          acc[m][n] = zz;
        }
      }
    }
  }

  f16* P = outP + (size_t)bz * (2ull * 512 * RTOT) + (size_t)model * 512 * RTOT;
#pragma unroll
  for (int m = 0; m < 4; ++m) {
    int R0 = r0 + wr * 64 + m * 16 + (kg << 2);
#pragma unroll
    for (int n = 0; n < 4; ++n) {
      int o = c0 + wc * 64 + n * 16 + lr;
      union { f16 h[4]; uint2 u; } pk;
      pk.h[0] = (f16)crun[m][n].x; pk.h[1] = (f16)crun[m][n].y;
      pk.h[2] = (f16)crun[m][n].z; pk.h[3] = (f16)crun[m][n].w;
      *(uint2*)(P + (size_t)o * RTOT + R0) = pk.u;
    }
  }
}

// ---------------- MLP GEMMs (modes 2,3, both models via by) ----------
template<int MODE, int MR, int NR>
__global__ __launch_bounds__(256, (MODE == 2) ? 3 : 4)
void k_gemm(const f16* __restrict__ Ain, const f16* __restrict__ Bin,
            const f16* auxAin, const f16* auxBin, f16* __restrict__ outIn) {
  __shared__ __align__(16) f16 As[MR * 32 * 64];
  __shared__ __align__(16) f16 Bs[NR * 32 * 64];
  const int tid = threadIdx.x, l = tid & 63, wvi = tid >> 6;
  const int wr = wvi >> 1, wc = wvi & 1;
  const int bx = blockIdx.x, byi = blockIdx.y;
  constexpr int BYD = (MODE == 2) ? 32 : 8;      // y-blocks per model
  const int model = byi / BYD, by = byi % BYD;
  const int r0 = by * (MR * 32), c0 = bx * (NR * 32);
  constexpr int KS = (MODE == 2) ? 8 : 32;
  const size_t actOff = (size_t)model * 2048 * 512;
  const f16* A = Ain + (size_t)model * ((MODE == 2) ? 4096ull * 512 : 512ull * 2048);
  const f16* B0 = Bin + ((MODE == 2) ? actOff : (size_t)model * 2048 * 2048);
  const f16* auxA = auxAin + actOff;
  const f16* auxB = auxBin + actOff;
  f16* outH = outIn + ((MODE == 2) ? (size_t)model * 2048 * 2048 : actOff);

  f32x4 acc[MR][NR];
  f32x4 zz = {0.f, 0.f, 0.f, 0.f};
#pragma unroll
  for (int m = 0; m < MR; ++m)
#pragma unroll
    for (int n = 0; n < NR; ++n) acc[m][n] = zz;

  for (int s = 0; s < KS; ++s) {
    __syncthreads();
    stage<MODE, MR, NR>(A, B0, r0, c0, tid, s, As, Bs);
    __syncthreads();
    mma_step<MR, NR>(As, Bs, l, wr, wc, acc);
  }

  if constexpr (MODE == 2) {
#pragma unroll
    for (int m = 0; m < MR; ++m) {
      int jj0 = r0 + wr * (MR * 16) + m * 16 + ((l >> 4) << 2);
      int h2 = jj0 >> 1;
#pragma unroll
      for (int n = 0; n < NR; ++n) {
        int r = c0 + wc * (NR * 16) + n * 16 + (l & 15);
        f32x4 a = acc[m][n];
        float v0 = a.x * (a.y / (1.f + __expf(-a.y)));
        float v1 = a.z * (a.w / (1.f + __expf(-a.w)));
        union { f16 h[2]; unsigned u; } pk;
        pk.h[0] = (f16)v0; pk.h[1] = (f16)v1;
        *(unsigned*)(outH + (size_t)r * 2048 + h2) = pk.u;
      }
    }
  } else {
#pragma unroll
    for (int m = 0; m < MR; ++m) {
      int o0 = r0 + wr * (MR * 16) + m * 16 + ((l >> 4) << 2);
#pragma unroll
      for (int n = 0; n < NR; ++n) {
        int r = c0 + wc * (NR * 16) + n * 16 + (l & 15);
        union { uint2 u; f16 h[4]; } xv, x1v;
        xv.u  = *(const uint2*)(auxA + (size_t)r * 512 + o0);
        x1v.u = *(const uint2*)(auxB + (size_t)r * 512 + o0);
        f32x4 a = acc[m][n];
        union { f16 h[4]; uint2 u; } pk;
        pk.h[0] = (f16)((float)xv.h[0] + (float)x1v.h[0] + a.x);
        pk.h[1] = (f16)((float)xv.h[1] + (float)x1v.h[1] + a.y);
        pk.h[2] = (f16)((float)xv.h[2] + (float)x1v.h[2] + a.z);
        pk.h[3] = (f16)((float)xv.h[3] + (float)x1v.h[3] + a.w);
        *(uint2*)(outH + (size_t)r * 512 + o0) = pk.u;
      }
    }
  }
}

// ---------------- inproj (0..4095) + Wu cast for all 4 model-layers (4096..4863) ----------
__global__ __launch_bounds__(256)
void k_inproj(const float* __restrict__ inp, const float* __restrict__ Wall,
              const float* __restrict__ Mu, f16* __restrict__ x, f16* __restrict__ WuAll) {
  __shared__ __align__(16) char smem[16900];
  int wg = (int)blockIdx.x, tid = threadIdx.x;
  if (wg < 4096) {
    float* row = (float*)smem;
    int r = wg;
    int model = r >> 11, rl = r & 2047;
    const float* W = Wall + (size_t)model * 512 * 64;
    if (tid < 64) row[tid] = inp[(size_t)rl * 64 + tid];
    __syncthreads();
    for (int o = tid; o < 512; o += 256) {
      const float* wr = W + (size_t)o * 64;
      float acc = 0.f;
#pragma unroll 8
      for (int q = 0; q < 64; ++q) acc += row[q] * wr[q];
      x[(size_t)r * 512 + o] = (f16)acc;
    }
    return;
  }
  // Wu cast: Wu[li][model][o][ip*512+d] = mu[ml][2-ip][d][o]
  float* T = (float*)smem;
  int q = wg - 4096;                   // 0..767
  int lm = q & 3;
  int model = lm & 1, li = lm >> 1;
  int blk = q >> 2;                    // 0..191
  int ip = blk >> 6, tile = blk & 63;
  int d0 = (tile >> 3) * 64, o0 = (tile & 7) * 64;
  const float* src = Mu + ((size_t)(model * 2 + li) * 3 + (2 - ip)) * 262144;
  f16* dst = WuAll + ((size_t)li * 2 + model) * (512ull * 1536);
  for (int p = tid; p < 4096; p += 256) {
    int i = p >> 6, j = p & 63;
    T[i * 65 + j] = src[(size_t)(d0 + i) * 512 + o0 + j];
  }
  __syncthreads();
  for (int p = tid; p < 4096; p += 256) {
    int i = p >> 6, j = p & 63;
    dst[(size_t)(o0 + i) * 1536 + ip * 512 + d0 + j] = (f16)T[j * 65 + i];
  }
}

// out[r] = x_m0[r] @ W0^T + x_m1[r] @ W1^T  (single kernel, both models)
__global__ void k_outproj(const f16* __restrict__ x, const float* __restrict__ Wall,
                          float* out) {
  __shared__ float row[1024];
  int r = blockIdx.x, tid = threadIdx.x;
  for (int i = tid; i < 1024; i += 256) {
    int mdl = i >> 9, c = i & 511;
    row[i] = (float)x[((size_t)mdl * 2048 + r) * 512 + c];
  }
  __syncthreads();
  int o = tid >> 2, part = tid & 3;
  const float* w0 = Wall + (size_t)o * 512 + part * 128;
  const float* w1 = Wall + 64ull * 512 + (size_t)o * 512 + part * 128;
  const float* r0 = row + part * 128;
  const float* r1 = row + 512 + part * 128;
  float acc = 0.f;
#pragma unroll 16
  for (int q = 0; q < 128; ++q) acc += r0[q] * w0[q] + r1[q] * w1[q];
  acc += __shfl_xor(acc, 1, 64);
  acc += __shfl_xor(acc, 2, 64);
  if (part == 0) out[(size_t)r * 64 + o] = acc;
}

// ---------------- host ----------------
extern "C" void kernel_launch(void* const* d_in, const int* in_sizes, int n_in,
                              void* d_out, int out_size, void* d_ws, size_t ws_size,
                              hipStream_t stream) {
  const float* inputs    = (const float*)d_in[0];
  const float* sigma     = (const float*)d_in[1];
  const float* phi       = (const float*)d_in[2];
  const float* in_proj_w = (const float*)d_in[3];
  const float* rn_w      = (const float*)d_in[4];
  const float* M_u       = (const float*)d_in[5];
  const float* M_phi_p   = (const float*)d_in[6];
  const float* M_phi_m   = (const float*)d_in[7];
  const float* fc1       = (const float*)d_in[8];
  const float* fc2       = (const float*)d_in[9];
  const float* out_proj_w= (const float*)d_in[10];
  float* out = (float*)d_out;

  char* ws = (char*)d_ws;
  size_t off = 0;
  auto alloc = [&](size_t bytes) -> void* {
    void* p = ws + off;
    off += (bytes + 255) & ~(size_t)255;
    return p;
  };
  float2* tw   = (float2*)alloc(1024 * 8);
  float2* Vf   = (float2*)alloc((size_t)16 * 1025 * 8);
  float2* cpcm = (float2*)alloc((size_t)32 * CPS * 8);
  f16*    x    = (f16*)alloc((size_t)2 * NROW * 512 * 2);
  f16*    hb2  = (f16*)alloc((size_t)4 * 1026 * 512 * 2);   // 2 models x 2 batches
  f16*    x1p  = (f16*)alloc((size_t)2 * NROW * 512 * 2);
  f16*    x1   = (f16*)alloc((size_t)2 * NROW * 512 * 2);
  f16*    Xbf  = (f16*)alloc((size_t)2 * RTOT * 512 * 2);
  f16*    P    = (f16*)alloc((size_t)NPART * 2 * 512 * RTOT * 2);
  f16*    g1   = (f16*)alloc((size_t)2 * NROW * 2048 * 2);
  f16*    Wsp  = (f16*)alloc((size_t)2 * 16384 * 512 * 2);
  f16*    WuA  = (f16*)alloc((size_t)4 * 512 * 1536 * 2);   // [li][model]
  f16*    Wf1  = (f16*)alloc((size_t)2 * 4096 * 512 * 2);
  f16*    Wf2  = (f16*)alloc((size_t)2 * 512 * 2048 * 2);
  if (off > ws_size) return;  // workspace too small: fail loudly (output stays poisoned)

  // zero the AR window pad rows (rows 0,1 of each of the 4 batch blocks)
  for (int k = 0; k < 4; ++k)
    hipMemsetAsync(hb2 + (size_t)k * 1026 * 512, 0, 2 * 512 * sizeof(f16), stream);
  k_twiddle<<<4, 256, 0, stream>>>(tw);
  k_fft_phi<<<8, 256, 0, stream>>>(phi, Vf, tw);
  k_cpcm<<<133, 256, 0, stream>>>(Vf, sigma, cpcm);

  k_inproj<<<4096 + 768, 256, 0, stream>>>(inputs, in_proj_w, M_u, x, WuA);
  for (int li = 0; li < 2; ++li) {
    k_rmsnorm<<<1024, 256, 0, stream>>>(x, rn_w, li, hb2);
    k_fwdcast<<<1024 + 512 + 7168, 256, 0, stream>>>(
        hb2, Xbf, tw, li, M_phi_p, M_phi_m, fc1, fc2, Wsp, WuA, Wf1, Wf2, x, x1p);
    k_gemm0<<<dim3(512), 256, 0, stream>>>(Xbf, Wsp, (const float*)cpcm, P);
    k_fft_inv<<<1024, 256, 0, stream>>>(P, x1p, x1, tw);
    k_gemm<2, 4, 4><<<dim3(16, 64), 256, 0, stream>>>(Wf1, x1, nullptr, nullptr, g1);
    k_gemm<3, 2, 2><<<dim3(32, 16), 256, 0, stream>>>(Wf2, g1, x, x1, x);
  }
  k_outproj<<<NROW, 256, 0, stream>>>(x, out_proj_w, out);
}

// Round 17
// 732.023 us; speedup vs baseline: 1.1316x; 1.0073x over previous
//
#include <hip/hip_runtime.h>
#include <hip/hip_bf16.h>

typedef _Float16 f16;
typedef _Float16 half8 __attribute__((ext_vector_type(8)));
typedef float f32x4 __attribute__((ext_vector_type(4)));

#define S_LEN 1024
#define DMODEL 512
#define NFFT   2048
#define RPB    2048     // rows per batch: f=1..1023 pairs + packed (DC.re, Nyq.re) in rows 0,1
#define RTOT   4096     // per-model: 2 batches -> exactly 32 row-tiles of 128
#define CPS    1064     // cpcm f-stride
#define NROW   2048     // B*S per model
#define NPART  2        // split-K partials (gemm0 grid 512 = exactly 1 generation)

__device__ __forceinline__ float2 mkf2(float a, float b) { float2 r; r.x = a; r.y = b; return r; }
__device__ __forceinline__ int zp(int i) { return i + (i >> 5); }   // LDS bank-pad for FFT array
__device__ __forceinline__ float2 cmul(float2 w, float2 b) {
  return mkf2(b.x * w.x - b.y * w.y, b.x * w.y + b.y * w.x);
}
__device__ __forceinline__ float2 f2a(float2 a, float2 b) { return mkf2(a.x + b.x, a.y + b.y); }
__device__ __forceinline__ float2 f2s(float2 a, float2 b) { return mkf2(a.x - b.x, a.y - b.y); }

// async global->LDS (16B per lane). LDS dest must be wave-uniform base; lane writes at +lane*16.
__device__ __forceinline__ void gl16(const f16* g, f16* l) {
  __builtin_amdgcn_global_load_lds((const __attribute__((address_space(1))) void*)g,
                                   (__attribute__((address_space(3))) void*)l, 16, 0, 0);
}

// ---------------- FFT-2048 in LDS: 3x radix-8 + 1x radix-4, padded indexing ----------------
template<bool INV>
__device__ __forceinline__ void fft2048(float2* z, const float2* __restrict__ tw, int tid) {
  for (int i = tid; i < 2048; i += 256) {
    int j = (int)(__brev((unsigned)i) >> 21);
    if (i < j) { float2 a = z[zp(i)]; z[zp(i)] = z[zp(j)]; z[zp(j)] = a; }
  }
  __syncthreads();
#pragma unroll
  for (int r8 = 0; r8 < 3; ++r8) {       // fused stages (1,2,3),(4,5,6),(7,8,9)
    const int sl = 1 + 3 * r8;
    const int h = 1 << (sl - 1);
    {
      int q = tid;                        // 256 groups of 8, one per thread
      int j = q & (h - 1);
      int i0 = ((q >> (sl - 1)) << (sl + 2)) + j;
      float2 a0 = z[zp(i0)],         a1 = z[zp(i0 + h)];
      float2 a2 = z[zp(i0 + 2 * h)], a3 = z[zp(i0 + 3 * h)];
      float2 a4 = z[zp(i0 + 4 * h)], a5 = z[zp(i0 + 5 * h)];
      float2 a6 = z[zp(i0 + 6 * h)], a7 = z[zp(i0 + 7 * h)];
      float2 wA  = tw[j << (11 - sl)];
      float2 wB0 = tw[j << (10 - sl)];
      float2 wB1 = tw[(j + h) << (10 - sl)];
      float2 wC0 = tw[j << (9 - sl)];
      float2 wC1 = tw[(j + h) << (9 - sl)];
      float2 wC2 = tw[(j + 2 * h) << (9 - sl)];
      float2 wC3 = tw[(j + 3 * h) << (9 - sl)];
      if (INV) {
        wA.y = -wA.y; wB0.y = -wB0.y; wB1.y = -wB1.y;
        wC0.y = -wC0.y; wC1.y = -wC1.y; wC2.y = -wC2.y; wC3.y = -wC3.y;
      }
      float2 t;
      t = cmul(wA, a1); float2 b0 = f2a(a0, t), b1 = f2s(a0, t);
      t = cmul(wA, a3); float2 b2 = f2a(a2, t), b3 = f2s(a2, t);
      t = cmul(wA, a5); float2 b4 = f2a(a4, t), b5 = f2s(a4, t);
      t = cmul(wA, a7); float2 b6 = f2a(a6, t), b7 = f2s(a6, t);
      t = cmul(wB0, b2); float2 c0 = f2a(b0, t), c2 = f2s(b0, t);
      t = cmul(wB1, b3); float2 c1 = f2a(b1, t), c3 = f2s(b1, t);
      t = cmul(wB0, b6); float2 c4 = f2a(b4, t), c6 = f2s(b4, t);
      t = cmul(wB1, b7); float2 c5 = f2a(b5, t), c7 = f2s(b5, t);
      t = cmul(wC0, c4); z[zp(i0)]         = f2a(c0, t); z[zp(i0 + 4 * h)] = f2s(c0, t);
      t = cmul(wC1, c5); z[zp(i0 + h)]     = f2a(c1, t); z[zp(i0 + 5 * h)] = f2s(c1, t);
      t = cmul(wC2, c6); z[zp(i0 + 2 * h)] = f2a(c2, t); z[zp(i0 + 6 * h)] = f2s(c2, t);
      t = cmul(wC3, c7); z[zp(i0 + 3 * h)] = f2a(c3, t); z[zp(i0 + 7 * h)] = f2s(c3, t);
    }
    __syncthreads();
  }
  for (int q = tid; q < 512; q += 256) {  // final radix-4 round: stages (10,11)
    float2 a0 = z[zp(q)], a1 = z[zp(q + 512)], a2 = z[zp(q + 1024)], a3 = z[zp(q + 1536)];
    float2 w1 = tw[q << 1], w2 = tw[q], w3 = tw[q + 512];
    if (INV) { w1.y = -w1.y; w2.y = -w2.y; w3.y = -w3.y; }
    float2 t;
    t = cmul(w1, a1); float2 b0 = f2a(a0, t), b1 = f2s(a0, t);
    t = cmul(w1, a3); float2 b2 = f2a(a2, t), b3 = f2s(a2, t);
    t = cmul(w2, b2); z[zp(q)]        = f2a(b0, t); z[zp(q + 1024)] = f2s(b0, t);
    t = cmul(w3, b3); z[zp(q + 512)]  = f2a(b1, t); z[zp(q + 1536)] = f2s(b1, t);
  }
  __syncthreads();
}

// ---------------- init kernels ----------------
__global__ void k_twiddle(float2* tw) {
  int i = blockIdx.x * 256 + threadIdx.x;
  if (i < 1024) {
    float ang = -6.2831853071795864769f * (float)i / 2048.0f;
    tw[i] = mkf2(cosf(ang), sinf(ang));
  }
}

// rfft of phi columns (pairs packed into one complex FFT)
__global__ void k_fft_phi(const float* __restrict__ phi, float2* __restrict__ Vf,
                          const float2* __restrict__ tw) {
  __shared__ float2 z[2112];
  int tid = threadIdx.x;
  int k0 = blockIdx.x * 2;
  for (int t = tid; t < 1024; t += 256)
    z[zp(t)] = *(const float2*)(phi + (size_t)t * 16 + k0);
  for (int t = 1024 + tid; t < 2048; t += 256) z[zp(t)] = mkf2(0.f, 0.f);
  __syncthreads();
  fft2048<false>(z, tw, tid);
  for (int f = tid; f <= 1024; f += 256) {
    float2 zf = z[zp(f)], zc = z[zp((2048 - f) & 2047)];
    Vf[(size_t)k0 * 1025 + f]       = mkf2(0.5f * (zf.x + zc.x), 0.5f * (zf.y - zc.y));
    Vf[(size_t)(k0 + 1) * 1025 + f] = mkf2(0.5f * (zf.y + zc.y), 0.5f * (zc.x - zf.x));
  }
}

// cpcm[kb][f]: f=1..1023 standard complex scale; slot 0 packs (c_DC, c_Nyq) (both REAL).
__global__ void k_cpcm(const float2* __restrict__ Vf, const float* __restrict__ sigma,
                       float2* __restrict__ cpcm) {
  int idx = blockIdx.x * 256 + threadIdx.x;
  if (idx >= 32 * CPS) return;
  int kb = idx / CPS, f = idx - kb * CPS;
  int k = kb & 15;
  float s = powf(sigma[k], 0.25f) * (1.0f / 2048.0f);
  float2 v = mkf2(0.f, 0.f);
  if (f == 0) {
    float dc = Vf[(size_t)k * 1025].x;          // real
    float ny = Vf[(size_t)k * 1025 + 1024].x;   // real
    v = (kb < 16) ? mkf2(s * dc, s * ny) : mkf2(s * ny, s * dc);
  } else if (f <= 1023) {
    if (kb < 16) {
      v = Vf[(size_t)k * 1025 + f];
    } else {
      float2 t = Vf[(size_t)k * 1025 + (1024 - f)];
      v = mkf2(t.x, -t.y);
    }
    v.x *= s; v.y *= s;
  }
  cpcm[idx] = v;
}

// ---------------- generic GEMM helpers (BK=64) ----------------
template<int MODE, int MR, int NR>
__device__ __forceinline__ void stage(const f16* __restrict__ A, const f16* __restrict__ B0,
                                      int r0, int c0, int tid, int s,
                                      f16* As, f16* Bs) {
  constexpr int LDA = (MODE == 1) ? 1536 : (MODE == 2) ? 512 : 2048;
  const int kA = s * 64;
  const int rowl = tid >> 3;
  const int lc8 = ((tid & 7) ^ (rowl & 7)) * 8;   // swizzled chunk * 8 (f16)
  f16* lA = As + ((tid >> 6) << 9);
  f16* lB = Bs + ((tid >> 6) << 9);
#pragma unroll
  for (int i = 0; i < MR; ++i) {
    int row = i * 32 + rowl;
    gl16(A + (size_t)(r0 + row) * LDA + kA + lc8, lA + i * 2048);
  }
#pragma unroll
  for (int i = 0; i < NR; ++i) {
    int row = i * 32 + rowl;
    const f16* bs;
    if constexpr (MODE == 1) {
      int ip = s >> 3, d0 = (s & 7) * 64;
      int rr = c0 + row;
      int b = rr >> 10, t = rr & 1023;
      bs = B0 + (size_t)(b * 1026 + t + ip) * 512 + d0 + lc8;   // pad rows are zero
    } else {
      constexpr int LDB = (MODE == 2) ? 512 : 2048;
      bs = B0 + (size_t)(c0 + row) * LDB + s * 64 + lc8;
    }
    gl16(bs, lB + i * 2048);
  }
}

template<int MR, int NR>
__device__ __forceinline__ void mma_step(const f16* As, const f16* Bs, int l, int wr, int wc,
                                         f32x4 acc[MR][NR]) {
  const int lr = l & 15, kg = l >> 4, sw = l & 7;
#pragma unroll
  for (int kk = 0; kk < 2; ++kk) {
    half8 af[MR], bf[NR];
    const int pc8 = (((kk * 4 + kg) ^ sw) << 3);
#pragma unroll
    for (int m = 0; m < MR; ++m)
      af[m] = *(const half8*)(As + (wr * (MR * 16) + m * 16 + lr) * 64 + pc8);
#pragma unroll
    for (int n = 0; n < NR; ++n)
      bf[n] = *(const half8*)(Bs + (wc * (NR * 16) + n * 16 + lr) * 64 + pc8);
#pragma unroll
    for (int m = 0; m < MR; ++m)
#pragma unroll
      for (int n = 0; n < NR; ++n)
        acc[m][n] = __builtin_amdgcn_mfma_f32_16x16x32_f16(af[m], bf[n], acc[m][n], 0, 0, 0);
  }
}

// ---------------- merged per-layer: fwd FFT (0..1023) + AR gemm1 (1024..1535) + cast ----------
// All three depend only on prior-launch outputs (hb2, x, pre-cast Wu) -> safe same-launch merge.
// gemm1 writes x1p = x + AR(h); spec is added later inside fft_inv.
__global__ __launch_bounds__(256)
void k_fwdcast(const f16* __restrict__ hb2, f16* __restrict__ Xbf,
               const float2* __restrict__ tw, int li,
               const float* __restrict__ Mp, const float* __restrict__ Mm,
               const float* __restrict__ Fc1, const float* __restrict__ Fc2,
               f16* __restrict__ Wsp, const f16* __restrict__ WuAll,
               f16* __restrict__ Wf1, f16* __restrict__ Wf2,
               const f16* __restrict__ x, f16* __restrict__ x1p) {
  __shared__ __align__(16) char smem[16896];
  int wg = (int)blockIdx.x, tid = threadIdx.x;
  if (wg < 1024) {
    // ---- forward FFT of hb2 -> Xbf; rows 0,1 = (DC.re, Nyq.re), rows 2f,2f+1 f=1..1023
    float2* z = (float2*)smem;
    int model = wg >> 9;
    int b = (wg >> 8) & 1;
    int d0 = (wg & 255) * 2;
    const f16* hsrc = hb2 + (size_t)(model * 2 + b) * 1026 * 512;
    f16* xdst = Xbf + (size_t)model * RTOT * 512 + (size_t)b * RPB * 512;
    for (int t = tid; t < 1024; t += 256) {
      union { unsigned v; f16 q[2]; } w;
      w.v = *(const unsigned*)(hsrc + (size_t)(2 + t) * 512 + d0);
      z[zp(t)] = mkf2((float)w.q[0], (float)w.q[1]);
    }
    for (int t = 1024 + tid; t < 2048; t += 256) z[zp(t)] = mkf2(0.f, 0.f);
    __syncthreads();
    fft2048<false>(z, tw, tid);
    for (int f = tid; f <= 1024; f += 256) {
      float2 zf = z[zp(f)], zc = z[zp((2048 - f) & 2047)];
      float x0r = 0.5f * (zf.x + zc.x), x0i = 0.5f * (zf.y - zc.y);
      float x1r = 0.5f * (zf.y + zc.y), x1i = 0.5f * (zc.x - zf.x);
      union { f16 h2[2]; unsigned u; } pr, pi;
      pr.h2[0] = (f16)x0r; pr.h2[1] = (f16)x1r;
      pi.h2[0] = (f16)x0i; pi.h2[1] = (f16)x1i;
      if (f == 0) {
        *(unsigned*)(xdst + d0) = pr.u;                                  // DC (im=0)
      } else if (f == 1024) {
        *(unsigned*)(xdst + (size_t)512 + d0) = pr.u;                    // Nyquist (im=0)
      } else {
        *(unsigned*)(xdst + (size_t)(2 * f) * 512 + d0)     = pr.u;
        *(unsigned*)(xdst + (size_t)(2 * f + 1) * 512 + d0) = pi.u;
      }
    }
    return;
  }
  if (wg < 1536) {
    // ---- AR gemm1 (MODE 1): x1p = x + AR(h), 64x64 tiles, KS=24
    f16* As = (f16*)smem;
    f16* Bs = (f16*)smem + 4096;
    int q = wg - 1024;
    const int bx = q & 31, byi = q >> 5;
    const int model = byi >> 3, by = byi & 7;
    const int r0 = by * 64, c0 = bx * 64;
    const int l = tid & 63, wvi = tid >> 6;
    const int wr = wvi >> 1, wc = wvi & 1;
    const f16* A  = WuAll + ((size_t)li * 2 + model) * (512ull * 1536);
    const f16* B0 = hb2 + (size_t)model * 2 * 1026 * 512;
    const f16* xM  = x  + (size_t)model * 2048 * 512;
    f16* x1pM      = x1p + (size_t)model * 2048 * 512;

    f32x4 acc[2][2];
    f32x4 zz = {0.f, 0.f, 0.f, 0.f};
#pragma unroll
    for (int m = 0; m < 2; ++m)
#pragma unroll
      for (int n = 0; n < 2; ++n) acc[m][n] = zz;

    for (int s = 0; s < 24; ++s) {
      __syncthreads();
      stage<1, 2, 2>(A, B0, r0, c0, tid, s, As, Bs);
      __syncthreads();
      mma_step<2, 2>(As, Bs, l, wr, wc, acc);
    }
#pragma unroll
    for (int m = 0; m < 2; ++m) {
      int o0 = r0 + wr * 32 + m * 16 + ((l >> 4) << 2);
#pragma unroll
      for (int n = 0; n < 2; ++n) {
        int r = c0 + wc * 32 + n * 16 + (l & 15);
        union { uint2 u; f16 h[4]; } xv;
        xv.u = *(const uint2*)(xM + (size_t)r * 512 + o0);
        f32x4 a = acc[m][n];
        union { f16 h[4]; uint2 u; } pk;
        pk.h[0] = (f16)((float)xv.h[0] + a.x);
        pk.h[1] = (f16)((float)xv.h[1] + a.y);
        pk.h[2] = (f16)((float)xv.h[2] + a.z);
        pk.h[3] = (f16)((float)xv.h[3] + a.w);
        *(uint2*)(x1pM + (size_t)r * 512 + o0) = pk.u;
      }
    }
    return;
  }
  // ---- weight cast/transpose for BOTH models (Wsp, fc1, fc2), T[64][65] in smem
  float* T = (float*)smem;
  int q0all = wg - 1536;               // 0..7167
  int model = q0all & 1;
  int blk = q0all >> 1;                // 0..3583
  int ml = model * 2 + li;
  const float* mp  = Mp  + (size_t)ml * 16 * 262144;
  const float* mm  = Mm  + (size_t)ml * 16 * 262144;
  const float* fc1 = Fc1 + (size_t)ml * 4096 * 512;
  const float* fc2 = Fc2 + (size_t)ml * 512 * 2048;
  f16* WspM = Wsp + (size_t)model * 16384 * 512;
  f16* Wf1M = Wf1 + (size_t)model * 4096 * 512;
  f16* Wf2M = Wf2 + (size_t)model * 512 * 2048;
  if (blk < 2048) {                    // Wsp: Wsp[(kb*512+o)][d] = m?[k][d][o]
    int mat = blk >> 6, tile = blk & 63;
    int d0 = (tile >> 3) * 64, o0 = (tile & 7) * 64;
    const float* src = (mat < 16) ? (mp + (size_t)mat * 262144)
                                  : (mm + (size_t)(mat - 16) * 262144);
    for (int q = tid; q < 4096; q += 256) {
      int i = q >> 6, j = q & 63;
      T[i * 65 + j] = src[(size_t)(d0 + i) * 512 + o0 + j];
    }
    __syncthreads();
    for (int q = tid; q < 4096; q += 256) {
      int i = q >> 6, j = q & 63;
      WspM[(size_t)(mat * 512 + o0 + i) * 512 + d0 + j] = (f16)T[j * 65 + i];
    }
  } else if (blk < 3072) {             // fc1 perm copy: row 2h = y-row h, 2h+1 = gate-row h
    int q1 = blk - 2048;
    size_t e = ((size_t)q1 * 256 + tid) * 8;
    int jj = (int)(e >> 9), col = (int)(e & 511);
    int srow = (jj & 1) ? (2048 + (jj >> 1)) : (jj >> 1);
    const float4* s = (const float4*)(fc1 + (size_t)srow * 512 + col);
    float4 a = s[0], b = s[1];
    union { f16 h[8]; uint4 u; } pk;
    pk.h[0] = (f16)a.x; pk.h[1] = (f16)a.y; pk.h[2] = (f16)a.z; pk.h[3] = (f16)a.w;
    pk.h[4] = (f16)b.x; pk.h[5] = (f16)b.y; pk.h[6] = (f16)b.z; pk.h[7] = (f16)b.w;
    *(uint4*)(Wf1M + (size_t)jj * 512 + col) = pk.u;
  } else {                             // fc2 straight copy (already [o][j])
    int q1 = blk - 3072;
    size_t e = ((size_t)q1 * 256 + tid) * 8;
    const float4* s = (const float4*)(fc2 + e);
    float4 a = s[0], b = s[1];
    union { f16 h[8]; uint4 u; } pk;
    pk.h[0] = (f16)a.x; pk.h[1] = (f16)a.y; pk.h[2] = (f16)a.z; pk.h[3] = (f16)a.w;
    pk.h[4] = (f16)b.x; pk.h[5] = (f16)b.y; pk.h[6] = (f16)b.z; pk.h[7] = (f16)b.w;
    *(uint4*)(Wf2M + e) = pk.u;
  }
}

// ---------------- rmsnorm both models (grid 1024) ----------------
__global__ void k_rmsnorm(const f16* __restrict__ x, const float* __restrict__ rn_w, int li,
                          f16* __restrict__ hb2) {
  int tid = threadIdx.x, l = tid & 63, wv = tid >> 6;
  int r = blockIdx.x * 4 + wv;           // 0..4095 global row
  int model = r >> 11;
  int rl = r & 2047;
  int b = rl >> 10, t = rl & 1023;
  const float* w = rn_w + (size_t)(model * 2 + li) * 512;
  const f16* xr = x + (size_t)r * 512;
  f16* hr = hb2 + (size_t)((model * 2 + b) * 1026 + 2 + t) * 512;
  float v[8]; float ss = 0.f;
#pragma unroll
  for (int j = 0; j < 8; ++j) { v[j] = (float)xr[j * 64 + l]; ss += v[j] * v[j]; }
#pragma unroll
  for (int o = 32; o; o >>= 1) ss += __shfl_xor(ss, o, 64);
  float rn = rsqrtf(ss * (1.f / 512.f) + 1e-5f);
#pragma unroll
  for (int j = 0; j < 8; ++j) {
    float hv = v[j] * rn * w[j * 64 + l];
    hr[j * 64 + l] = (f16)hv;
  }
}

// ---------------- inverse FFT both models: sum NPART partials, fuse x1 = x1p + spec ----------
__global__ void k_fft_inv(const f16* __restrict__ P, const f16* __restrict__ x1p,
                          f16* __restrict__ x1, const float2* __restrict__ tw) {
  __shared__ float2 z[2112];
  int tid = threadIdx.x;
  int wg = (int)blockIdx.x;
  int model = wg >> 9;
  int b = (wg >> 8) & 1;
  int o0 = (wg & 255) * 2;
  const f16* Pm = P + (size_t)model * 512 * RTOT;
  for (int fp = tid; fp < 512; fp += 256) {
    int f0 = fp * 2;
    size_t base0 = (size_t)o0 * RTOT + (size_t)b * RPB + 2 * f0;
    float s0r[2] = {0.f, 0.f}, s0i[2] = {0.f, 0.f};
    float s1r[2] = {0.f, 0.f}, s1i[2] = {0.f, 0.f};
#pragma unroll
    for (int g = 0; g < NPART; ++g) {
      const f16* Pg = Pm + (size_t)g * (2ull * 512 * RTOT);
      union { uint2 u; f16 h[4]; } ua, uc;
      ua.u = *(const uint2*)(Pg + base0);
      uc.u = *(const uint2*)(Pg + base0 + RTOT);
      s0r[0] += (float)ua.h[0]; s0i[0] += (float)ua.h[1];
      s0r[1] += (float)ua.h[2]; s0i[1] += (float)ua.h[3];
      s1r[0] += (float)uc.h[0]; s1i[0] += (float)uc.h[1];
      s1r[1] += (float)uc.h[2]; s1i[1] += (float)uc.h[3];
    }
    if (fp == 0) {
      z[zp(0)]    = mkf2(s0r[0], s1r[0]);   // DC of both real o-channels
      z[zp(1024)] = mkf2(s0i[0], s1i[0]);   // Nyquist of both
    } else {
      z[zp(f0)]        = mkf2(s0r[0] - s1i[0], s0i[0] + s1r[0]);
      z[zp(2048 - f0)] = mkf2(s0r[0] + s1i[0], s1r[0] - s0i[0]);
    }
    int f1 = f0 + 1;
    z[zp(f1)]        = mkf2(s0r[1] - s1i[1], s0i[1] + s1r[1]);
    z[zp(2048 - f1)] = mkf2(s0r[1] + s1i[1], s1r[1] - s0i[1]);
  }
  __syncthreads();
  fft2048<true>(z, tw, tid);
  size_t rowOff = (size_t)(model * 2048 + b * 1024) * 512;
  const f16* psrc = x1p + rowOff;
  f16* pdst = x1 + rowOff;
  for (int t = tid; t < 1024; t += 256) {
    float2 v = z[zp(t)];
    union { unsigned u; f16 h[2]; } pv;
    pv.u = *(const unsigned*)(psrc + (size_t)t * 512 + o0);
    union { f16 h[2]; unsigned u; } pk;
    pk.h[0] = (f16)((float)pv.h[0] + v.x);
    pk.h[1] = (f16)((float)pv.h[1] + v.y);
    *(unsigned*)(pdst + (size_t)t * 512 + o0) = pk.u;
  }
}

// ---------------- gemm0: spectral GEMM both models, NPART=2, super-steps of BK=128 ----------
// Two independent 64-wide LDS tiles per super-step, each with the proven conflict-free
// 8-chunk swizzle. Halves barrier count; kb constant per super-step.
__global__ __launch_bounds__(256, 2)
void k_gemm0(const f16* __restrict__ A0, const f16* __restrict__ B00,
             const float* __restrict__ aux0, f16* __restrict__ outP) {
  __shared__ __align__(16) f16 As[2][128 * 64];
  __shared__ __align__(16) f16 Bs[2][128 * 64];
  const int tid = threadIdx.x, l = tid & 63, wvi = tid >> 6;
  const int wr = wvi >> 1, wc = wvi & 1;
  int wg = (int)blockIdx.x;            // 512 = 8 * 64, bijective XCD chunk swizzle
  wg = (wg & 7) * 64 + (wg >> 3);
  const int model = wg >> 8;
  int rem = wg & 255;
  const int bz = rem >> 7; rem &= 127;
  const int by = rem >> 2, bx = rem & 3;
  const int r0 = by * 128, c0 = bx * 128;
  const f16* A  = A0  + (size_t)model * RTOT * 512;
  const f16* B0 = B00 + (size_t)model * 16384 * 512;

  f32x4 acc[4][4];
  f32x4 crun[4][4];
  f32x4 zz = {0.f, 0.f, 0.f, 0.f};
#pragma unroll
  for (int m = 0; m < 4; ++m)
#pragma unroll
    for (int n = 0; n < 4; ++n) { acc[m][n] = zz; crun[m][n] = zz; }

  const int rowl = tid >> 3;
  const int lc8 = ((tid & 7) ^ (rowl & 7)) * 8;   // swizzled chunk * 8 (f16)
  const int wvOff = (tid >> 6) << 9;
  const int lr = l & 15, kg = l >> 4, sw = l & 7;

  for (int ss = 0; ss < 64; ++ss) {    // super-step = 2 BK=64 steps, same kb
    __syncthreads();                   // prior mma's LDS reads done
    {
      const int s0 = ss * 2;
      const int kb = bz * 16 + (ss >> 2);
      const f16* Abase = A + (size_t)(r0 + rowl) * 512 + lc8;
      const f16* Bbase = B0 + (size_t)(kb * 512 + c0 + rowl) * 512 + lc8;
#pragma unroll
      for (int h = 0; h < 2; ++h) {
        const int kA = ((s0 + h) & 7) * 64;
        f16* lA = As[h] + wvOff;
        f16* lB = Bs[h] + wvOff;
#pragma unroll
        for (int i = 0; i < 4; ++i) {
          gl16(Abase + (size_t)(i * 32) * 512 + kA, lA + i * 2048);
          gl16(Bbase + (size_t)(i * 32) * 512 + kA, lB + i * 2048);
        }
      }
    }
    __syncthreads();                   // staging landed (compiler drains vmcnt)
#pragma unroll
    for (int h = 0; h < 2; ++h) {
#pragma unroll
      for (int kk = 0; kk < 2; ++kk) {
        half8 af[4], bf[4];
        const int pc8 = (((kk * 4 + kg) ^ sw) << 3);
#pragma unroll
        for (int m = 0; m < 4; ++m)
          af[m] = *(const half8*)(As[h] + (wr * 64 + m * 16 + lr) * 64 + pc8);
#pragma unroll
        for (int n = 0; n < 4; ++n)
          bf[n] = *(const half8*)(Bs[h] + (wc * 64 + n * 16 + lr) * 64 + pc8);
#pragma unroll
        for (int m = 0; m < 4; ++m)
#pragma unroll
          for (int n = 0; n < 4; ++n)
            acc[m][n] = __builtin_amdgcn_mfma_f32_16x16x32_f16(af[m], bf[n], acc[m][n], 0, 0, 0);
      }
    }
    if ((ss & 3) == 3) {               // per-kb complex rescale into running sum
      int kb = bz * 16 + (ss >> 2);
#pragma unroll
      for (int m = 0; m < 4; ++m) {
        int R = r0 + wr * 64 + m * 16 + (kg << 2);
        int rb = R & (RPB - 1);
        bool dc = (rb == 0);           // rows 0,1 = packed (DC.re, Nyq.re): scale separately
        float4 cs = *(const float4*)(aux0 + (size_t)kb * (CPS * 2) + (rb >> 1) * 2);
        float t1 = dc ? 0.f : cs.y;
        float t2 = dc ? cs.y : cs.x;
#pragma unroll
        for (int n = 0; n < 4; ++n) {
          f32x4 p = acc[m][n];
          crun[m][n].x += cs.x * p.x - t1 * p.y;
          crun[m][n].y += t2 * p.y + t1 * p.x;
          crun[m][n].z += cs.z * p.z - cs.w * p.w;
          crun[m][n].w += cs.z * p.w + cs.w * p.z;
          acc[m][n] = zz;
        }
      }
    }
  }

  f16* P = outP + (size_t)bz * (2ull * 512 * RTOT) + (size_t)model * 512 * RTOT;
#pragma unroll
  for (int m = 0; m < 4; ++m) {
    int R0 = r0 + wr * 64 + m * 16 + (kg << 2);
#pragma unroll
    for (int n = 0; n < 4; ++n) {
      int o = c0 + wc * 64 + n * 16 + lr;
      union { f16 h[4]; uint2 u; } pk;
      pk.h[0] = (f16)crun[m][n].x; pk.h[1] = (f16)crun[m][n].y;
      pk.h[2] = (f16)crun[m][n].z; pk.h[3] = (f16)crun[m][n].w;
      *(uint2*)(P + (size_t)o * RTOT + R0) = pk.u;
    }
  }
}

// ---------------- MLP GEMMs (modes 2,3, both models via by) ----------
// MODE 3 uses the two-half super-step (halved barriers; LDS 32KB keeps 4/CU).
template<int MODE, int MR, int NR>
__global__ __launch_bounds__(256, (MODE == 2) ? 3 : 4)
void k_gemm(const f16* __restrict__ Ain, const f16* __restrict__ Bin,
            const f16* auxAin, const f16* auxBin, f16* __restrict__ outIn) {
  constexpr int NH = (MODE == 3) ? 2 : 1;
  __shared__ __align__(16) f16 As[NH][MR * 32 * 64];
  __shared__ __align__(16) f16 Bs[NH][NR * 32 * 64];
  const int tid = threadIdx.x, l = tid & 63, wvi = tid >> 6;
  const int wr = wvi >> 1, wc = wvi & 1;
  const int bx = blockIdx.x, byi = blockIdx.y;
  constexpr int BYD = (MODE == 2) ? 32 : 8;      // y-blocks per model
  const int model = byi / BYD, by = byi % BYD;
  const int r0 = by * (MR * 32), c0 = bx * (NR * 32);
  constexpr int KS = (MODE == 2) ? 8 : 32;
  constexpr int NSS = KS / NH;
  const size_t actOff = (size_t)model * 2048 * 512;
  const f16* A = Ain + (size_t)model * ((MODE == 2) ? 4096ull * 512 : 512ull * 2048);
  const f16* B0 = Bin + ((MODE == 2) ? actOff : (size_t)model * 2048 * 2048);
  const f16* auxA = auxAin + actOff;
  const f16* auxB = auxBin + actOff;
  f16* outH = outIn + ((MODE == 2) ? (size_t)model * 2048 * 2048 : actOff);

  f32x4 acc[MR][NR];
  f32x4 zz = {0.f, 0.f, 0.f, 0.f};
#pragma unroll
  for (int m = 0; m < MR; ++m)
#pragma unroll
    for (int n = 0; n < NR; ++n) acc[m][n] = zz;

  for (int ss = 0; ss < NSS; ++ss) {
    __syncthreads();
#pragma unroll
    for (int h = 0; h < NH; ++h)
      stage<MODE, MR, NR>(A, B0, r0, c0, tid, ss * NH + h, As[h], Bs[h]);
    __syncthreads();
#pragma unroll
    for (int h = 0; h < NH; ++h)
      mma_step<MR, NR>(As[h], Bs[h], l, wr, wc, acc);
  }

  if constexpr (MODE == 2) {
#pragma unroll
    for (int m = 0; m < MR; ++m) {
      int jj0 = r0 + wr * (MR * 16) + m * 16 + ((l >> 4) << 2);
      int h2 = jj0 >> 1;
#pragma unroll
      for (int n = 0; n < NR; ++n) {
        int r = c0 + wc * (NR * 16) + n * 16 + (l & 15);
        f32x4 a = acc[m][n];
        float v0 = a.x * (a.y / (1.f + __expf(-a.y)));
        float v1 = a.z * (a.w / (1.f + __expf(-a.w)));
        union { f16 h[2]; unsigned u; } pk;
        pk.h[0] = (f16)v0; pk.h[1] = (f16)v1;
        *(unsigned*)(outH + (size_t)r * 2048 + h2) = pk.u;
      }
    }
  } else {
#pragma unroll
    for (int m = 0; m < MR; ++m) {
      int o0 = r0 + wr * (MR * 16) + m * 16 + ((l >> 4) << 2);
#pragma unroll
      for (int n = 0; n < NR; ++n) {
        int r = c0 + wc * (NR * 16) + n * 16 + (l & 15);
        union { uint2 u; f16 h[4]; } xv, x1v;
        xv.u  = *(const uint2*)(auxA + (size_t)r * 512 + o0);
        x1v.u = *(const uint2*)(auxB + (size_t)r * 512 + o0);
        f32x4 a = acc[m][n];
        union { f16 h[4]; uint2 u; } pk;
        pk.h[0] = (f16)((float)xv.h[0] + (float)x1v.h[0] + a.x);
        pk.h[1] = (f16)((float)xv.h[1] + (float)x1v.h[1] + a.y);
        pk.h[2] = (f16)((float)xv.h[2] + (float)x1v.h[2] + a.z);
        pk.h[3] = (f16)((float)xv.h[3] + (float)x1v.h[3] + a.w);
        *(uint2*)(outH + (size_t)r * 512 + o0) = pk.u;
      }
    }
  }
}

// ---------------- inproj (0..4095) + Wu cast for all 4 model-layers (4096..4863) ----------
__global__ __launch_bounds__(256)
void k_inproj(const float* __restrict__ inp, const float* __restrict__ Wall,
              const float* __restrict__ Mu, f16* __restrict__ x, f16* __restrict__ WuAll) {
  __shared__ __align__(16) char smem[16900];
  int wg = (int)blockIdx.x, tid = threadIdx.x;
  if (wg < 4096) {
    float* row = (float*)smem;
    int r = wg;
    int model = r >> 11, rl = r & 2047;
    const float* W = Wall + (size_t)model * 512 * 64;
    if (tid < 64) row[tid] = inp[(size_t)rl * 64 + tid];
    __syncthreads();
    for (int o = tid; o < 512; o += 256) {
      const float* wr = W + (size_t)o * 64;
      float acc = 0.f;
#pragma unroll 8
      for (int q = 0; q < 64; ++q) acc += row[q] * wr[q];
      x[(size_t)r * 512 + o] = (f16)acc;
    }
    return;
  }
  // Wu cast: Wu[li][model][o][ip*512+d] = mu[ml][2-ip][d][o]
  float* T = (float*)smem;
  int q = wg - 4096;                   // 0..767
  int lm = q & 3;
  int model = lm & 1, li = lm >> 1;
  int blk = q >> 2;                    // 0..191
  int ip = blk >> 6, tile = blk & 63;
  int d0 = (tile >> 3) * 64, o0 = (tile & 7) * 64;
  const float* src = Mu + ((size_t)(model * 2 + li) * 3 + (2 - ip)) * 262144;
  f16* dst = WuAll + ((size_t)li * 2 + model) * (512ull * 1536);
  for (int p = tid; p < 4096; p += 256) {
    int i = p >> 6, j = p & 63;
    T[i * 65 + j] = src[(size_t)(d0 + i) * 512 + o0 + j];
  }
  __syncthreads();
  for (int p = tid; p < 4096; p += 256) {
    int i = p >> 6, j = p & 63;
    dst[(size_t)(o0 + i) * 1536 + ip * 512 + d0 + j] = (f16)T[j * 65 + i];
  }
}

// out[r] = x_m0[r] @ W0^T + x_m1[r] @ W1^T  (single kernel, both models)
__global__ void k_outproj(const f16* __restrict__ x, const float* __restrict__ Wall,
                          float* out) {
  __shared__ float row[1024];
  int r = blockIdx.x, tid = threadIdx.x;
  for (int i = tid; i < 1024; i += 256) {
    int mdl = i >> 9, c = i & 511;
    row[i] = (float)x[((size_t)mdl * 2048 + r) * 512 + c];
  }
  __syncthreads();
  int o = tid >> 2, part = tid & 3;
  const float* w0 = Wall + (size_t)o * 512 + part * 128;
  const float* w1 = Wall + 64ull * 512 + (size_t)o * 512 + part * 128;
  const float* r0 = row + part * 128;
  const float* r1 = row + 512 + part * 128;
  float acc = 0.f;
#pragma unroll 16
  for (int q = 0; q < 128; ++q) acc += r0[q] * w0[q] + r1[q] * w1[q];
  acc += __shfl_xor(acc, 1, 64);
  acc += __shfl_xor(acc, 2, 64);
  if (part == 0) out[(size_t)r * 64 + o] = acc;
}

// ---------------- host ----------------
extern "C" void kernel_launch(void* const* d_in, const int* in_sizes, int n_in,
                              void* d_out, int out_size, void* d_ws, size_t ws_size,
                              hipStream_t stream) {
  const float* inputs    = (const float*)d_in[0];
  const float* sigma     = (const float*)d_in[1];
  const float* phi       = (const float*)d_in[2];
  const float* in_proj_w = (const float*)d_in[3];
  const float* rn_w      = (const float*)d_in[4];
  const float* M_u       = (const float*)d_in[5];
  const float* M_phi_p   = (const float*)d_in[6];
  const float* M_phi_m   = (const float*)d_in[7];
  const float* fc1       = (const float*)d_in[8];
  const float* fc2       = (const float*)d_in[9];
  const float* out_proj_w= (const float*)d_in[10];
  float* out = (float*)d_out;

  char* ws = (char*)d_ws;
  size_t off = 0;
  auto alloc = [&](size_t bytes) -> void* {
    void* p = ws + off;
    off += (bytes + 255) & ~(size_t)255;
    return p;
  };
  float2* tw   = (float2*)alloc(1024 * 8);
  float2* Vf   = (float2*)alloc((size_t)16 * 1025 * 8);
  float2* cpcm = (float2*)alloc((size_t)32 * CPS * 8);
  f16*    x    = (f16*)alloc((size_t)2 * NROW * 512 * 2);
  f16*    hb2  = (f16*)alloc((size_t)4 * 1026 * 512 * 2);   // 2 models x 2 batches
  f16*    x1p  = (f16*)alloc((size_t)2 * NROW * 512 * 2);
  f16*    x1   = (f16*)alloc((size_t)2 * NROW * 512 * 2);
  f16*    Xbf  = (f16*)alloc((size_t)2 * RTOT * 512 * 2);
  f16*    P    = (f16*)alloc((size_t)NPART * 2 * 512 * RTOT * 2);
  f16*    g1   = (f16*)alloc((size_t)2 * NROW * 2048 * 2);
  f16*    Wsp  = (f16*)alloc((size_t)2 * 16384 * 512 * 2);
  f16*    WuA  = (f16*)alloc((size_t)4 * 512 * 1536 * 2);   // [li][model]
  f16*    Wf1  = (f16*)alloc((size_t)2 * 4096 * 512 * 2);
  f16*    Wf2  = (f16*)alloc((size_t)2 * 512 * 2048 * 2);
  if (off > ws_size) return;  // workspace too small: fail loudly (output stays poisoned)

  // zero the AR window pad rows (rows 0,1 of each of the 4 batch blocks)
  for (int k = 0; k < 4; ++k)
    hipMemsetAsync(hb2 + (size_t)k * 1026 * 512, 0, 2 * 512 * sizeof(f16), stream);
  k_twiddle<<<4, 256, 0, stream>>>(tw);
  k_fft_phi<<<8, 256, 0, stream>>>(phi, Vf, tw);
  k_cpcm<<<133, 256, 0, stream>>>(Vf, sigma, cpcm);

  k_inproj<<<4096 + 768, 256, 0, stream>>>(inputs, in_proj_w, M_u, x, WuA);
  for (int li = 0; li < 2; ++li) {
    k_rmsnorm<<<1024, 256, 0, stream>>>(x, rn_w, li, hb2);
    k_fwdcast<<<1024 + 512 + 7168, 256, 0, stream>>>(
        hb2, Xbf, tw, li, M_phi_p, M_phi_m, fc1, fc2, Wsp, WuA, Wf1, Wf2, x, x1p);
    k_gemm0<<<dim3(512), 256, 0, stream>>>(Xbf, Wsp, (const float*)cpcm, P);
    k_fft_inv<<<1024, 256, 0, stream>>>(P, x1p, x1, tw);
    k_gemm<2, 4, 4><<<dim3(16, 64), 256, 0, stream>>>(Wf1, x1, nullptr, nullptr, g1);
    k_gemm<3, 2, 2><<<dim3(32, 16), 256, 0, stream>>>(Wf2, g1, x, x1, x);
  }
  k_outproj<<<NROW, 256, 0, stream>>>(x, out_proj_w, out);
}